// Round 1
// baseline (550.598 us; speedup 1.0000x reference)
//
#include <hip/hip_runtime.h>
#include <math.h>

#define D 512
#define M 128
#define B 16
#define KSEL 4
#define NC 2048           // M*B
#define NTOK 4096         // 2*2048
#define TT 8              // tokens per block in token kernel

// ws layout (floats)
#define WS_EACC   0       // [128]  energy accumulator
#define WS_CACC   128     // [128]  count accumulator
#define WS_VSUM   256     // [1]    sum |Gv - I|
#define WS_USUM   257     // [1]    sum |Gu - I|
#define WS_VSCALE 512     // [2048] 1/||V col||
#define WS_USCALE 2560    // [2048] tanh(us)/||U col||

// out layout (floats)
#define OUT_X    0
#define OUT_TE   2097152
#define OUT_EPE  2097153
#define OUT_RE   2097281
#define OUT_SR   2097409
#define OUT_VPEN 2097537
#define OUT_UPEN 2097538
#define OUT_AUX  2097539

__global__ void init_ws_kernel(float* __restrict__ ws) {
    int i = blockIdx.x * 256 + threadIdx.x;
    if (i < 512) ws[i] = 0.0f;
}

// blocks 0..7: vscale columns; blocks 8..15: uscale columns
__global__ void scales_kernel(const float* __restrict__ V,
                              const float* __restrict__ U,
                              const float* __restrict__ us_in,
                              float* __restrict__ ws) {
    int c = blockIdx.x * 256 + threadIdx.x;
    if (c < NC) {
        float s = 0.0f;
        const float* p = V + c;
        for (int d = 0; d < D; ++d) { float v = p[(size_t)d * NC]; s = fmaf(v, v, s); }
        ws[WS_VSCALE + c] = 1.0f / sqrtf(s);
    } else {
        int c2 = c - NC;
        int m = c2 >> 4, b = c2 & 15;
        float s = 0.0f;
        const float* p = U + (size_t)m * (D * B) + b;
        for (int d = 0; d < D; ++d) { float v = p[(size_t)d * B]; s = fmaf(v, v, s); }
        ws[WS_USCALE + c2] = tanhf(us_in[c2]) / sqrtf(s);
    }
}

// Fused: reprs GEMM -> energies -> top4 -> energy/count atomics -> writes -> out
__launch_bounds__(256)
__global__ void token_kernel(const float* __restrict__ x,
                             const float* __restrict__ V,
                             const float* __restrict__ U,
                             const float* __restrict__ ws,
                             float* __restrict__ out) {
    __shared__ __attribute__((aligned(16))) float xs[D][TT];   // 16 KB, [d][t]
    __shared__ float en[TT][M];                                 // 4 KB
    __shared__ int   sidx[TT][KSEL];
    __shared__ float w[TT][64];                                 // 2 KB: uscale*r for selected cols

    const int tid = threadIdx.x;
    const int t0 = blockIdx.x * TT;

    // ---- phase 0: load x tile (coalesced), zero energies ----
#pragma unroll
    for (int k2 = 0; k2 < (TT * D) / 256; ++k2) {
        int e = k2 * 256 + tid;
        int t = e >> 9, d = e & 511;
        xs[d][t] = x[(size_t)(t0 + t) * D + d];
    }
#pragma unroll
    for (int k2 = 0; k2 < (TT * M) / 256; ++k2) {
        ((float*)en)[k2 * 256 + tid] = 0.0f;
    }
    __syncthreads();

    // ---- phase 1: 8-token x 8-col register-tile GEMM over d ----
    const int col_base = tid << 3;   // 8 consecutive columns per thread
    float acc[TT][8];
#pragma unroll
    for (int t = 0; t < TT; ++t)
#pragma unroll
        for (int j = 0; j < 8; ++j) acc[t][j] = 0.0f;

    const float* Vp = V + col_base;
    for (int d = 0; d < D; ++d) {
        float4 va = *(const float4*)(Vp);
        float4 vb = *(const float4*)(Vp + 4);
        Vp += NC;
        float4 xa = *(const float4*)(&xs[d][0]);
        float4 xb = *(const float4*)(&xs[d][4]);
        float vv[8] = {va.x, va.y, va.z, va.w, vb.x, vb.y, vb.z, vb.w};
        float xv[8] = {xa.x, xa.y, xa.z, xa.w, xb.x, xb.y, xb.z, xb.w};
#pragma unroll
        for (int t = 0; t < TT; ++t)
#pragma unroll
            for (int j = 0; j < 8; ++j)
                acc[t][j] = fmaf(xv[t], vv[j], acc[t][j]);
    }

    // scale and accumulate energy per (t, m); m = col_base/16 = tid/2
    float vs[8];
#pragma unroll
    for (int j = 0; j < 8; ++j) vs[j] = ws[WS_VSCALE + col_base + j];
    const int my_m = tid >> 1;
#pragma unroll
    for (int t = 0; t < TT; ++t) {
        float s = 0.0f;
#pragma unroll
        for (int j = 0; j < 8; ++j) {
            float r = acc[t][j] * vs[j];
            s = fmaf(r, r, s);
        }
        atomicAdd(&en[t][my_m], s);
    }
    __syncthreads();

    // ---- phase 2: top-4 per token (exact jax tie-break: strict >, asc scan) ----
    if (tid < TT) {
        float bv0 = -1e30f, bv1 = -1e30f, bv2 = -1e30f, bv3 = -1e30f;
        int bi0 = 0, bi1 = 0, bi2 = 0, bi3 = 0;
        for (int m = 0; m < M; ++m) {
            float v = en[tid][m];
            if (v > bv3) {
                if (v > bv0) {
                    bv3 = bv2; bi3 = bi2; bv2 = bv1; bi2 = bi1; bv1 = bv0; bi1 = bi0;
                    bv0 = v; bi0 = m;
                } else if (v > bv1) {
                    bv3 = bv2; bi3 = bi2; bv2 = bv1; bi2 = bi1;
                    bv1 = v; bi1 = m;
                } else if (v > bv2) {
                    bv3 = bv2; bi3 = bi2;
                    bv2 = v; bi2 = m;
                } else {
                    bv3 = v; bi3 = m;
                }
            }
        }
        sidx[tid][0] = bi0; sidx[tid][1] = bi1; sidx[tid][2] = bi2; sidx[tid][3] = bi3;
        float* e_acc = (float*)ws + WS_EACC;   // ws is const in sig; cast for atomics
        float* c_acc = (float*)ws + WS_CACC;
        atomicAdd(&e_acc[bi0], bv0); atomicAdd(&c_acc[bi0], 1.0f);
        atomicAdd(&e_acc[bi1], bv1); atomicAdd(&c_acc[bi1], 1.0f);
        atomicAdd(&e_acc[bi2], bv2); atomicAdd(&c_acc[bi2], 1.0f);
        atomicAdd(&e_acc[bi3], bv3); atomicAdd(&c_acc[bi3], 1.0f);
    }
    __syncthreads();

    // ---- phase 3: recompute r for selected columns, build w = r*vscale*uscale ----
    {
        const int j = tid & 63;       // selected-column slot (k*16+b)
        const int tset = tid >> 6;    // 0..3
#pragma unroll
        for (int pass = 0; pass < 2; ++pass) {
            int t = (pass << 2) + tset;
            int e = sidx[t][j >> 4];
            int c = (e << 4) + (j & 15);
            const float* Vq = V + c;
            float a0 = 0.0f, a1 = 0.0f, a2 = 0.0f, a3 = 0.0f;
            for (int d = 0; d < D; d += 4) {
                a0 = fmaf(xs[d + 0][t], Vq[(size_t)(d + 0) * NC], a0);
                a1 = fmaf(xs[d + 1][t], Vq[(size_t)(d + 1) * NC], a1);
                a2 = fmaf(xs[d + 2][t], Vq[(size_t)(d + 2) * NC], a2);
                a3 = fmaf(xs[d + 3][t], Vq[(size_t)(d + 3) * NC], a3);
            }
            float a = (a0 + a1) + (a2 + a3);
            w[t][j] = a * ws[WS_VSCALE + c] * ws[WS_USCALE + c];
        }
    }
    __syncthreads();

    // ---- phase 4: writes + residual, coalesced over d ----
    for (int t = 0; t < TT; ++t) {
#pragma unroll
        for (int dh = 0; dh < 2; ++dh) {
            int d = (dh << 8) + tid;
            float acc4[KSEL];
#pragma unroll
            for (int k = 0; k < KSEL; ++k) {
                int e = sidx[t][k];
                const float4* Up = (const float4*)(U + (size_t)e * (D * B) + (size_t)d * B);
                float4 u0 = Up[0], u1 = Up[1], u2 = Up[2], u3 = Up[3];
                const float* wp = &w[t][k << 4];
                float s;
                s  = u0.x * wp[0]  + u0.y * wp[1]  + u0.z * wp[2]  + u0.w * wp[3];
                s += u1.x * wp[4]  + u1.y * wp[5]  + u1.z * wp[6]  + u1.w * wp[7];
                s += u2.x * wp[8]  + u2.y * wp[9]  + u2.z * wp[10] + u2.w * wp[11];
                s += u3.x * wp[12] + u3.y * wp[13] + u3.z * wp[14] + u3.w * wp[15];
                acc4[k] = s;
            }
            out[(size_t)(t0 + t) * D + d] =
                xs[d][t] + ((acc4[0] + acc4[1]) + (acc4[2] + acc4[3]));
        }
    }
}

// Gram |A^T A - I| sum over upper-triangle 64x64 tiles (x2 off-diagonal).
// mode 0: A is (D x NC) row-major (V).  mode 1: A is U (M, D, B); col = m*16+b.
__launch_bounds__(256)
__global__ void gram_kernel(const float* __restrict__ A,
                            const float* __restrict__ scales,
                            float* __restrict__ sum_out,
                            int mode) {
    int bi = blockIdx.x, bj = blockIdx.y;
    if (bi > bj) return;

    __shared__ __attribute__((aligned(16))) float As[32][64];
    __shared__ __attribute__((aligned(16))) float Bs[32][64];

    const int tid = threadIdx.x;
    const int r0 = (tid & 15) << 2;
    const int c0 = (tid >> 4) << 2;

    float acc[4][4];
#pragma unroll
    for (int ii = 0; ii < 4; ++ii)
#pragma unroll
        for (int jj = 0; jj < 4; ++jj) acc[ii][jj] = 0.0f;

    const int li = tid << 3;
    const int dd = li >> 6;     // 0..31
    const int cc = li & 63;

    for (int d0 = 0; d0 < D; d0 += 32) {
        if (mode == 0) {
            const float* pa = A + (size_t)(d0 + dd) * NC + bi * 64 + cc;
            *(float4*)&As[dd][cc]     = *(const float4*)(pa);
            *(float4*)&As[dd][cc + 4] = *(const float4*)(pa + 4);
            const float* pb = A + (size_t)(d0 + dd) * NC + bj * 64 + cc;
            *(float4*)&Bs[dd][cc]     = *(const float4*)(pb);
            *(float4*)&Bs[dd][cc + 4] = *(const float4*)(pb + 4);
        } else {
            int colA = bi * 64 + cc;
            const float* pa = A + (size_t)(colA >> 4) * (D * B) + (size_t)(d0 + dd) * B + (colA & 15);
            *(float4*)&As[dd][cc]     = *(const float4*)(pa);
            *(float4*)&As[dd][cc + 4] = *(const float4*)(pa + 4);
            int colB = bj * 64 + cc;
            const float* pb = A + (size_t)(colB >> 4) * (D * B) + (size_t)(d0 + dd) * B + (colB & 15);
            *(float4*)&Bs[dd][cc]     = *(const float4*)(pb);
            *(float4*)&Bs[dd][cc + 4] = *(const float4*)(pb + 4);
        }
        __syncthreads();
#pragma unroll
        for (int dd2 = 0; dd2 < 32; ++dd2) {
            float4 a4 = *(const float4*)&As[dd2][r0];
            float4 b4 = *(const float4*)&Bs[dd2][c0];
            float ar[4] = {a4.x, a4.y, a4.z, a4.w};
            float br[4] = {b4.x, b4.y, b4.z, b4.w};
#pragma unroll
            for (int ii = 0; ii < 4; ++ii)
#pragma unroll
                for (int jj = 0; jj < 4; ++jj)
                    acc[ii][jj] = fmaf(ar[ii], br[jj], acc[ii][jj]);
        }
        __syncthreads();
    }

    const int gi0 = bi * 64 + r0, gj0 = bj * 64 + c0;
    float si[4], sj[4];
#pragma unroll
    for (int ii = 0; ii < 4; ++ii) { si[ii] = scales[gi0 + ii]; sj[ii] = scales[gj0 + ii]; }

    float local = 0.0f;
#pragma unroll
    for (int ii = 0; ii < 4; ++ii)
#pragma unroll
        for (int jj = 0; jj < 4; ++jj) {
            float g = acc[ii][jj] * si[ii] * sj[jj];
            if (gi0 + ii == gj0 + jj) g -= 1.0f;
            local += fabsf(g);
        }
    if (bi != bj) local *= 2.0f;

#pragma unroll
    for (int off = 32; off > 0; off >>= 1) local += __shfl_down(local, off);
    __shared__ float red[4];
    if ((tid & 63) == 0) red[tid >> 6] = local;
    __syncthreads();
    if (tid == 0) atomicAdd(sum_out, (red[0] + red[1]) + (red[2] + red[3]));
}

__global__ void finalize_kernel(const float* __restrict__ ws, float* __restrict__ out) {
    const int m = threadIdx.x;   // 128 threads
    float e = ws[WS_EACC + m] * (1.0f / (float)NTOK);
    float c = ws[WS_CACC + m] * (1.0f / (float)NTOK);

    float s = e;
#pragma unroll
    for (int off = 32; off > 0; off >>= 1) s += __shfl_down(s, off);
    __shared__ float sh[2];
    if ((m & 63) == 0) sh[m >> 6] = s;
    __syncthreads();
    float total = sh[0] + sh[1];
    float total_energy = fmaxf(total, 1e-12f);

    out[OUT_EPE + m] = e;
    out[OUT_RE + m] = e / total_energy;
    out[OUT_SR + m] = c;
    if (m == 0) {
        out[OUT_TE] = total_energy;
        float inv_n2 = 1.0f / ((float)NC * (float)NC);
        float sqrtD = sqrtf((float)D);
        float vpen = ws[WS_VSUM] * inv_n2 * sqrtD;
        float upen = ws[WS_USUM] * inv_n2 * sqrtD;
        out[OUT_VPEN] = vpen;
        out[OUT_UPEN] = upen;
        out[OUT_AUX] = 0.01f * vpen - total_energy;
    }
}

extern "C" void kernel_launch(void* const* d_in, const int* in_sizes, int n_in,
                              void* d_out, int out_size, void* d_ws, size_t ws_size,
                              hipStream_t stream) {
    const float* x  = (const float*)d_in[0];
    const float* V  = (const float*)d_in[1];
    const float* U  = (const float*)d_in[2];
    const float* us = (const float*)d_in[3];
    float* out = (float*)d_out;
    float* ws  = (float*)d_ws;

    init_ws_kernel<<<2, 256, 0, stream>>>(ws);
    scales_kernel<<<16, 256, 0, stream>>>(V, U, us, ws);
    token_kernel<<<NTOK / TT, 256, 0, stream>>>(x, V, U, ws, out);
    gram_kernel<<<dim3(32, 32), 256, 0, stream>>>(V, ws + WS_VSCALE, ws + WS_VSUM, 0);
    gram_kernel<<<dim3(32, 32), 256, 0, stream>>>(U, ws + WS_USCALE, ws + WS_USUM, 1);
    finalize_kernel<<<1, 128, 0, stream>>>(ws, out);
}

// Round 2
// 523.037 us; speedup vs baseline: 1.0527x; 1.0527x over previous
//
#include <hip/hip_runtime.h>
#include <math.h>

#define D 512
#define M 128
#define B 16
#define KSEL 4
#define NC 2048           // M*B
#define NTOK 4096         // 2*2048
#define TT 8              // tokens per block in token kernel

// ws layout (floats)
#define WS_EACC   0       // [128]  energy accumulator
#define WS_CACC   128     // [128]  count accumulator
#define WS_VSUM   256     // [1]    sum |Gv - I|
#define WS_USUM   257     // [1]    sum |Gu - I|
#define WS_VSCALE 512     // [2048] 1/||V col||
#define WS_USCALE 2560    // [2048] tanh(us)/||U col||

// out layout (floats)
#define OUT_X    0
#define OUT_TE   2097152
#define OUT_EPE  2097153
#define OUT_RE   2097281
#define OUT_SR   2097409
#define OUT_VPEN 2097537
#define OUT_UPEN 2097538
#define OUT_AUX  2097539

__global__ void init_ws_kernel(float* __restrict__ ws) {
    int i = blockIdx.x * 256 + threadIdx.x;
    if (i < 512) ws[i] = 0.0f;
}

// blocks 0..7: vscale columns; blocks 8..15: uscale columns
__global__ void scales_kernel(const float* __restrict__ V,
                              const float* __restrict__ U,
                              const float* __restrict__ us_in,
                              float* __restrict__ ws) {
    int c = blockIdx.x * 256 + threadIdx.x;
    if (c < NC) {
        float s = 0.0f;
        const float* p = V + c;
        for (int d = 0; d < D; ++d) { float v = p[(size_t)d * NC]; s = fmaf(v, v, s); }
        ws[WS_VSCALE + c] = 1.0f / sqrtf(s);
    } else {
        int c2 = c - NC;
        int m = c2 >> 4, b = c2 & 15;
        float s = 0.0f;
        const float* p = U + (size_t)m * (D * B) + b;
        for (int d = 0; d < D; ++d) { float v = p[(size_t)d * B]; s = fmaf(v, v, s); }
        ws[WS_USCALE + c2] = tanhf(us_in[c2]) / sqrtf(s);
    }
}

// Fused: reprs GEMM -> energies -> top4 -> energy/count atomics -> writes -> out
// Owner-writes trick: the scaled reprs stay in the registers of the thread that
// computed them (thread tid owns cols [tid*8, tid*8+8)); after top-k the owning
// threads publish w = r*vscale*uscale to LDS directly -> no phase-3 recompute.
__launch_bounds__(256)
__global__ void token_kernel(const float* __restrict__ x,
                             const float* __restrict__ V,
                             const float* __restrict__ U,
                             const float* __restrict__ ws,
                             float* __restrict__ out) {
    __shared__ __attribute__((aligned(16))) float xs[D][TT];   // 16 KB, [d][t]
    __shared__ float en[TT][M];                                 // 4 KB
    __shared__ int   sidx[TT][KSEL];
    __shared__ float w[TT][64];                                 // 2 KB

    const int tid = threadIdx.x;
    const int t0 = blockIdx.x * TT;

    // ---- phase 0: load x tile (coalesced), zero energies ----
#pragma unroll
    for (int k2 = 0; k2 < (TT * D) / 256; ++k2) {
        int e = k2 * 256 + tid;
        int t = e >> 9, d = e & 511;
        xs[d][t] = x[(size_t)(t0 + t) * D + d];
    }
#pragma unroll
    for (int k2 = 0; k2 < (TT * M) / 256; ++k2) {
        ((float*)en)[k2 * 256 + tid] = 0.0f;
    }
    __syncthreads();

    // ---- phase 1: 8-token x 8-col register-tile GEMM over d, depth-2 prefetch ----
    const int col_base = tid << 3;   // 8 consecutive columns per thread
    float acc[TT][8];
#pragma unroll
    for (int t = 0; t < TT; ++t)
#pragma unroll
        for (int j = 0; j < 8; ++j) acc[t][j] = 0.0f;

    const float* Vp = V + col_base;
    float4 p0a = *(const float4*)(Vp), p0b = *(const float4*)(Vp + 4); Vp += NC;
    float4 p1a = *(const float4*)(Vp), p1b = *(const float4*)(Vp + 4); Vp += NC;

#pragma unroll 2
    for (int d = 0; d < D; ++d) {
        float4 ca = p0a, cb = p0b;
        p0a = p1a; p0b = p1b;
        if (d < D - 2) {
            p1a = *(const float4*)(Vp);
            p1b = *(const float4*)(Vp + 4);
            Vp += NC;
        }
        float4 xa = *(const float4*)(&xs[d][0]);
        float4 xb = *(const float4*)(&xs[d][4]);
        float vv[8] = {ca.x, ca.y, ca.z, ca.w, cb.x, cb.y, cb.z, cb.w};
        float xv[8] = {xa.x, xa.y, xa.z, xa.w, xb.x, xb.y, xb.z, xb.w};
#pragma unroll
        for (int t = 0; t < TT; ++t)
#pragma unroll
            for (int j = 0; j < 8; ++j)
                acc[t][j] = fmaf(xv[t], vv[j], acc[t][j]);
    }

    // fold vscale into acc (acc becomes the scaled repr), accumulate energy
    float vs[8];
#pragma unroll
    for (int j = 0; j < 8; ++j) vs[j] = ws[WS_VSCALE + col_base + j];
    const int my_m = tid >> 1;
#pragma unroll
    for (int t = 0; t < TT; ++t) {
        float s = 0.0f;
#pragma unroll
        for (int j = 0; j < 8; ++j) {
            acc[t][j] *= vs[j];
            s = fmaf(acc[t][j], acc[t][j], s);
        }
        atomicAdd(&en[t][my_m], s);
    }
    __syncthreads();

    // ---- phase 2: top-4 per token (exact jax tie-break: strict >, asc scan) ----
    if (tid < TT) {
        float bv0 = -1e30f, bv1 = -1e30f, bv2 = -1e30f, bv3 = -1e30f;
        int bi0 = 0, bi1 = 0, bi2 = 0, bi3 = 0;
        for (int m = 0; m < M; ++m) {
            float v = en[tid][m];
            if (v > bv3) {
                if (v > bv0) {
                    bv3 = bv2; bi3 = bi2; bv2 = bv1; bi2 = bi1; bv1 = bv0; bi1 = bi0;
                    bv0 = v; bi0 = m;
                } else if (v > bv1) {
                    bv3 = bv2; bi3 = bi2; bv2 = bv1; bi2 = bi1;
                    bv1 = v; bi1 = m;
                } else if (v > bv2) {
                    bv3 = bv2; bi3 = bi2;
                    bv2 = v; bi2 = m;
                } else {
                    bv3 = v; bi3 = m;
                }
            }
        }
        sidx[tid][0] = bi0; sidx[tid][1] = bi1; sidx[tid][2] = bi2; sidx[tid][3] = bi3;
        float* e_acc = (float*)ws + WS_EACC;
        float* c_acc = (float*)ws + WS_CACC;
        atomicAdd(&e_acc[bi0], bv0); atomicAdd(&c_acc[bi0], 1.0f);
        atomicAdd(&e_acc[bi1], bv1); atomicAdd(&c_acc[bi1], 1.0f);
        atomicAdd(&e_acc[bi2], bv2); atomicAdd(&c_acc[bi2], 1.0f);
        atomicAdd(&e_acc[bi3], bv3); atomicAdd(&c_acc[bi3], 1.0f);
    }
    __syncthreads();

    // ---- phase 3: owner threads publish w = scaled_repr * uscale ----
    {
        const int half = tid & 1;        // b 0-7 or 8-15 of expert my_m
        const int wslot = (half << 3);
#pragma unroll
        for (int t = 0; t < TT; ++t) {
#pragma unroll
            for (int k = 0; k < KSEL; ++k) {
                if (sidx[t][k] == my_m) {
                    const float* usc = ws + WS_USCALE + (my_m << 4) + wslot;
#pragma unroll
                    for (int j = 0; j < 8; ++j)
                        w[t][(k << 4) + wslot + j] = acc[t][j] * usc[j];
                }
            }
        }
    }
    __syncthreads();

    // ---- phase 4: writes + residual, coalesced over d ----
    for (int t = 0; t < TT; ++t) {
#pragma unroll
        for (int dh = 0; dh < 2; ++dh) {
            int d = (dh << 8) + tid;
            float acc4[KSEL];
#pragma unroll
            for (int k = 0; k < KSEL; ++k) {
                int e = sidx[t][k];
                const float4* Up = (const float4*)(U + (size_t)e * (D * B) + (size_t)d * B);
                float4 u0 = Up[0], u1 = Up[1], u2 = Up[2], u3 = Up[3];
                const float* wp = &w[t][k << 4];
                float s;
                s  = u0.x * wp[0]  + u0.y * wp[1]  + u0.z * wp[2]  + u0.w * wp[3];
                s += u1.x * wp[4]  + u1.y * wp[5]  + u1.z * wp[6]  + u1.w * wp[7];
                s += u2.x * wp[8]  + u2.y * wp[9]  + u2.z * wp[10] + u2.w * wp[11];
                s += u3.x * wp[12] + u3.y * wp[13] + u3.z * wp[14] + u3.w * wp[15];
                acc4[k] = s;
            }
            out[(size_t)(t0 + t) * D + d] =
                xs[d][t] + ((acc4[0] + acc4[1]) + (acc4[2] + acc4[3]));
        }
    }
}

// Gram |A^T A - I| sum over upper-triangle 64x64 tiles (x2 off-diagonal).
// mode 0: A is (D x NC) row-major (V).  mode 1: A is U (M, D, B); col = m*16+b.
// Register-staged prefetch: next k-tile is loaded to regs while FMAs run on LDS.
__launch_bounds__(256)
__global__ void gram_kernel(const float* __restrict__ A,
                            const float* __restrict__ scales,
                            float* __restrict__ sum_out,
                            int mode) {
    int bi = blockIdx.x, bj = blockIdx.y;
    if (bi > bj) return;

    __shared__ __attribute__((aligned(16))) float As[32][64];
    __shared__ __attribute__((aligned(16))) float Bs[32][64];

    const int tid = threadIdx.x;
    const int r0 = (tid & 15) << 2;
    const int c0 = (tid >> 4) << 2;

    float acc[4][4];
#pragma unroll
    for (int ii = 0; ii < 4; ++ii)
#pragma unroll
        for (int jj = 0; jj < 4; ++jj) acc[ii][jj] = 0.0f;

    const int li = tid << 3;
    const int dd = li >> 6;     // 0..31
    const int cc = li & 63;

    float4 ra0, ra1, rb0, rb1;
    auto load_regs = [&](int d0) {
        if (mode == 0) {
            const float* pa = A + (size_t)(d0 + dd) * NC + bi * 64 + cc;
            ra0 = *(const float4*)(pa);
            ra1 = *(const float4*)(pa + 4);
            const float* pb = A + (size_t)(d0 + dd) * NC + bj * 64 + cc;
            rb0 = *(const float4*)(pb);
            rb1 = *(const float4*)(pb + 4);
        } else {
            int colA = bi * 64 + cc;
            const float* pa = A + (size_t)(colA >> 4) * (D * B) + (size_t)(d0 + dd) * B + (colA & 15);
            ra0 = *(const float4*)(pa);
            ra1 = *(const float4*)(pa + 4);
            int colB = bj * 64 + cc;
            const float* pb = A + (size_t)(colB >> 4) * (D * B) + (size_t)(d0 + dd) * B + (colB & 15);
            rb0 = *(const float4*)(pb);
            rb1 = *(const float4*)(pb + 4);
        }
    };

    load_regs(0);
    for (int d0 = 0; d0 < D; d0 += 32) {
        *(float4*)&As[dd][cc]     = ra0;
        *(float4*)&As[dd][cc + 4] = ra1;
        *(float4*)&Bs[dd][cc]     = rb0;
        *(float4*)&Bs[dd][cc + 4] = rb1;
        __syncthreads();
        if (d0 + 32 < D) load_regs(d0 + 32);   // in flight during FMAs
#pragma unroll
        for (int dd2 = 0; dd2 < 32; ++dd2) {
            float4 a4 = *(const float4*)&As[dd2][r0];
            float4 b4 = *(const float4*)&Bs[dd2][c0];
            float ar[4] = {a4.x, a4.y, a4.z, a4.w};
            float br[4] = {b4.x, b4.y, b4.z, b4.w};
#pragma unroll
            for (int ii = 0; ii < 4; ++ii)
#pragma unroll
                for (int jj = 0; jj < 4; ++jj)
                    acc[ii][jj] = fmaf(ar[ii], br[jj], acc[ii][jj]);
        }
        __syncthreads();
    }

    const int gi0 = bi * 64 + r0, gj0 = bj * 64 + c0;
    float si[4], sj[4];
#pragma unroll
    for (int ii = 0; ii < 4; ++ii) { si[ii] = scales[gi0 + ii]; sj[ii] = scales[gj0 + ii]; }

    float local = 0.0f;
#pragma unroll
    for (int ii = 0; ii < 4; ++ii)
#pragma unroll
        for (int jj = 0; jj < 4; ++jj) {
            float g = acc[ii][jj] * si[ii] * sj[jj];
            if (gi0 + ii == gj0 + jj) g -= 1.0f;
            local += fabsf(g);
        }
    if (bi != bj) local *= 2.0f;

#pragma unroll
    for (int off = 32; off > 0; off >>= 1) local += __shfl_down(local, off);
    __shared__ float red[4];
    if ((tid & 63) == 0) red[tid >> 6] = local;
    __syncthreads();
    if (tid == 0) atomicAdd(sum_out, (red[0] + red[1]) + (red[2] + red[3]));
}

__global__ void finalize_kernel(const float* __restrict__ ws, float* __restrict__ out) {
    const int m = threadIdx.x;   // 128 threads
    float e = ws[WS_EACC + m] * (1.0f / (float)NTOK);
    float c = ws[WS_CACC + m] * (1.0f / (float)NTOK);

    float s = e;
#pragma unroll
    for (int off = 32; off > 0; off >>= 1) s += __shfl_down(s, off);
    __shared__ float sh[2];
    if ((m & 63) == 0) sh[m >> 6] = s;
    __syncthreads();
    float total = sh[0] + sh[1];
    float total_energy = fmaxf(total, 1e-12f);

    out[OUT_EPE + m] = e;
    out[OUT_RE + m] = e / total_energy;
    out[OUT_SR + m] = c;
    if (m == 0) {
        out[OUT_TE] = total_energy;
        float inv_n2 = 1.0f / ((float)NC * (float)NC);
        float sqrtD = sqrtf((float)D);
        float vpen = ws[WS_VSUM] * inv_n2 * sqrtD;
        float upen = ws[WS_USUM] * inv_n2 * sqrtD;
        out[OUT_VPEN] = vpen;
        out[OUT_UPEN] = upen;
        out[OUT_AUX] = 0.01f * vpen - total_energy;
    }
}

extern "C" void kernel_launch(void* const* d_in, const int* in_sizes, int n_in,
                              void* d_out, int out_size, void* d_ws, size_t ws_size,
                              hipStream_t stream) {
    const float* x  = (const float*)d_in[0];
    const float* V  = (const float*)d_in[1];
    const float* U  = (const float*)d_in[2];
    const float* us = (const float*)d_in[3];
    float* out = (float*)d_out;
    float* ws  = (float*)d_ws;

    init_ws_kernel<<<2, 256, 0, stream>>>(ws);
    scales_kernel<<<16, 256, 0, stream>>>(V, U, us, ws);
    token_kernel<<<NTOK / TT, 256, 0, stream>>>(x, V, U, ws, out);
    gram_kernel<<<dim3(32, 32), 256, 0, stream>>>(V, ws + WS_VSCALE, ws + WS_VSUM, 0);
    gram_kernel<<<dim3(32, 32), 256, 0, stream>>>(U, ws + WS_USCALE, ws + WS_USUM, 1);
    finalize_kernel<<<1, 128, 0, stream>>>(ws, out);
}

// Round 3
// 426.647 us; speedup vs baseline: 1.2905x; 1.2259x over previous
//
#include <hip/hip_runtime.h>
#include <math.h>

#define D 512
#define M 128
#define B 16
#define KSEL 4
#define NC 2048           // M*B
#define NTOK 4096         // 2*2048
#define TTB 4             // tokens per block in topk/write kernel

// ws layout (floats)
#define WS_EACC   0       // [128]
#define WS_CACC   128     // [128]
#define WS_VSUM   256     // [1]
#define WS_USUM   257     // [1]
#define WS_VSCALE 512     // [2048] 1/||V col||
#define WS_USCALE 2560    // [2048] tanh(us)/||U col||
#define WS_E      4608                    // [NTOK*M]  energies (4096x128), 2 MB
#define WS_R      (4608 + NTOK * M)       // [NTOK*NC] scaled reprs (4096x2048), 32 MB

// out layout (floats)
#define OUT_X    0
#define OUT_TE   2097152
#define OUT_EPE  2097153
#define OUT_RE   2097281
#define OUT_SR   2097409
#define OUT_VPEN 2097537
#define OUT_UPEN 2097538
#define OUT_AUX  2097539

__global__ void init_ws_kernel(float* __restrict__ ws) {
    int i = blockIdx.x * 256 + threadIdx.x;
    if (i < 512) ws[i] = 0.0f;
}

// Coalesced norms. blocks 0..31: V cols (64 per block). blocks 32..159: U expert m.
__global__ void scales_kernel(const float* __restrict__ V,
                              const float* __restrict__ U,
                              const float* __restrict__ us_in,
                              float* __restrict__ ws) {
    const int bx = blockIdx.x;
    const int tid = threadIdx.x;
    if (bx < 32) {
        const int c = bx * 64 + (tid & 63);
        const int dg = tid >> 6;
        float s = 0.0f;
        for (int d = dg; d < D; d += 4) {
            float v = V[(size_t)d * NC + c];
            s = fmaf(v, v, s);
        }
        __shared__ float sh[4][64];
        sh[dg][tid & 63] = s;
        __syncthreads();
        if (tid < 64) {
            float t = (sh[0][tid] + sh[1][tid]) + (sh[2][tid] + sh[3][tid]);
            ws[WS_VSCALE + bx * 64 + tid] = 1.0f / sqrtf(t);
        }
    } else {
        const int m = bx - 32;
        const float* p = U + (size_t)m * (D * B);
        float s = 0.0f;
        for (int i = tid; i < D * B; i += 256) {   // i&15 == tid&15: per-thread fixed b
            float v = p[i];
            s = fmaf(v, v, s);
        }
        __shared__ float sh2[256];
        sh2[tid] = s;
        __syncthreads();
        if (tid < 16) {
            float t = 0.0f;
#pragma unroll
            for (int j = 0; j < 16; ++j) t += sh2[tid + (j << 4)];
            ws[WS_USCALE + (m << 4) + tid] = tanhf(us_in[(m << 4) + tid]) / sqrtf(t);
        }
    }
}

// Tiled fp32 GEMM: R = (x @ V) * vscale  (128 tok x 128 col tiles), plus E per (tok, expert).
__launch_bounds__(256)
__global__ void gemm_kernel(const float* __restrict__ x,
                            const float* __restrict__ V,
                            float* __restrict__ ws) {
    __shared__ __attribute__((aligned(16))) float As[32][128];  // [k][tok]
    __shared__ __attribute__((aligned(16))) float Bs[32][128];  // [k][col], vscale folded

    const int tid = threadIdx.x;
    const int tok0 = blockIdx.x * 128;
    const int col0 = blockIdx.y * 128;

    // B-staging coords + vscale regs (reused all 16 tiles)
    const int sk = tid >> 3;            // 0..31
    const int scq = (tid & 7) << 4;     // 0,16,...,112
    float4 vs0 = *(const float4*)(ws + WS_VSCALE + col0 + scq);
    float4 vs1 = *(const float4*)(ws + WS_VSCALE + col0 + scq + 4);
    float4 vs2 = *(const float4*)(ws + WS_VSCALE + col0 + scq + 8);
    float4 vs3 = *(const float4*)(ws + WS_VSCALE + col0 + scq + 12);

    // A-staging coords
    const int at = tid >> 1;            // token 0..127
    const int akq = (tid & 1) << 4;     // k offset 0 or 16

    // compute coords: 8x8 thread tile
    const int tx = tid & 15, ty = tid >> 4;
    const int ct = ty << 3;             // token base
    const int cc = tx << 3;             // col base

    float acc[8][8];
#pragma unroll
    for (int i = 0; i < 8; ++i)
#pragma unroll
        for (int j = 0; j < 8; ++j) acc[i][j] = 0.0f;

    for (int k0 = 0; k0 < D; k0 += 32) {
        // global loads into regs (overlap with previous tile's compute)
        const float* xp = x + (size_t)(tok0 + at) * D + k0 + akq;
        float4 a0 = *(const float4*)(xp);
        float4 a1 = *(const float4*)(xp + 4);
        float4 a2 = *(const float4*)(xp + 8);
        float4 a3 = *(const float4*)(xp + 12);
        const float* vp = V + (size_t)(k0 + sk) * NC + col0 + scq;
        float4 b0 = *(const float4*)(vp);
        float4 b1 = *(const float4*)(vp + 4);
        float4 b2 = *(const float4*)(vp + 8);
        float4 b3 = *(const float4*)(vp + 12);
        b0.x *= vs0.x; b0.y *= vs0.y; b0.z *= vs0.z; b0.w *= vs0.w;
        b1.x *= vs1.x; b1.y *= vs1.y; b1.z *= vs1.z; b1.w *= vs1.w;
        b2.x *= vs2.x; b2.y *= vs2.y; b2.z *= vs2.z; b2.w *= vs2.w;
        b3.x *= vs3.x; b3.y *= vs3.y; b3.z *= vs3.z; b3.w *= vs3.w;

        __syncthreads();   // previous tile fully consumed
        {
            float av[16] = {a0.x, a0.y, a0.z, a0.w, a1.x, a1.y, a1.z, a1.w,
                            a2.x, a2.y, a2.z, a2.w, a3.x, a3.y, a3.z, a3.w};
#pragma unroll
            for (int j = 0; j < 16; ++j) As[akq + j][at] = av[j];
            *(float4*)&Bs[sk][scq]      = b0;
            *(float4*)&Bs[sk][scq + 4]  = b1;
            *(float4*)&Bs[sk][scq + 8]  = b2;
            *(float4*)&Bs[sk][scq + 12] = b3;
        }
        __syncthreads();

#pragma unroll
        for (int k = 0; k < 32; ++k) {
            float4 pa0 = *(const float4*)&As[k][ct];
            float4 pa1 = *(const float4*)&As[k][ct + 4];
            float4 pb0 = *(const float4*)&Bs[k][cc];
            float4 pb1 = *(const float4*)&Bs[k][cc + 4];
            float ar[8] = {pa0.x, pa0.y, pa0.z, pa0.w, pa1.x, pa1.y, pa1.z, pa1.w};
            float br[8] = {pb0.x, pb0.y, pb0.z, pb0.w, pb1.x, pb1.y, pb1.z, pb1.w};
#pragma unroll
            for (int i = 0; i < 8; ++i)
#pragma unroll
                for (int j = 0; j < 8; ++j)
                    acc[i][j] = fmaf(ar[i], br[j], acc[i][j]);
        }
    }

    // write R (scaled reprs)
#pragma unroll
    for (int i = 0; i < 8; ++i) {
        float* rp = ws + WS_R + (size_t)(tok0 + ct + i) * NC + col0 + cc;
        *(float4*)(rp)     = make_float4(acc[i][0], acc[i][1], acc[i][2], acc[i][3]);
        *(float4*)(rp + 4) = make_float4(acc[i][4], acc[i][5], acc[i][6], acc[i][7]);
    }

    // energies: block covers 128 toks x 8 experts
    __syncthreads();                     // done with As/Bs; reuse As as eE[128][8]
    float* eE = &As[0][0];
#pragma unroll
    for (int i = 0; i < 4; ++i) eE[i * 256 + tid] = 0.0f;
    __syncthreads();
    const int ml = tx >> 1;              // local expert 0..7
#pragma unroll
    for (int i = 0; i < 8; ++i) {
        float s = 0.0f;
#pragma unroll
        for (int j = 0; j < 8; ++j) s = fmaf(acc[i][j], acc[i][j], s);
        atomicAdd(&eE[(ct + i) * 8 + ml], s);
    }
    __syncthreads();
#pragma unroll
    for (int i = 0; i < 4; ++i) {
        int idx = i * 256 + tid;
        int t = idx >> 3, j = idx & 7;
        ws[WS_E + (size_t)(tok0 + t) * M + blockIdx.y * 8 + j] = eE[idx];
    }
}

// top-4 (exact jax semantics) + aux atomics + U-gather writes + residual
__launch_bounds__(256)
__global__ void topk_write_kernel(const float* __restrict__ x,
                                  const float* __restrict__ U,
                                  float* __restrict__ ws,
                                  float* __restrict__ out) {
    __shared__ float en[TTB][M];     // 2 KB
    __shared__ int   sidx[TTB][KSEL];
    __shared__ float w[TTB][64];

    const int tid = threadIdx.x;
    const int t0 = blockIdx.x * TTB;

#pragma unroll
    for (int i = 0; i < (TTB * M) / 256; ++i)
        ((float*)en)[i * 256 + tid] = ws[WS_E + (size_t)t0 * M + i * 256 + tid];
    __syncthreads();

    if (tid < TTB) {
        float bv0 = -1e30f, bv1 = -1e30f, bv2 = -1e30f, bv3 = -1e30f;
        int bi0 = 0, bi1 = 0, bi2 = 0, bi3 = 0;
        for (int m = 0; m < M; ++m) {
            float v = en[tid][m];
            if (v > bv3) {
                if (v > bv0) {
                    bv3 = bv2; bi3 = bi2; bv2 = bv1; bi2 = bi1; bv1 = bv0; bi1 = bi0;
                    bv0 = v; bi0 = m;
                } else if (v > bv1) {
                    bv3 = bv2; bi3 = bi2; bv2 = bv1; bi2 = bi1;
                    bv1 = v; bi1 = m;
                } else if (v > bv2) {
                    bv3 = bv2; bi3 = bi2;
                    bv2 = v; bi2 = m;
                } else {
                    bv3 = v; bi3 = m;
                }
            }
        }
        sidx[tid][0] = bi0; sidx[tid][1] = bi1; sidx[tid][2] = bi2; sidx[tid][3] = bi3;
        atomicAdd(&ws[WS_EACC + bi0], bv0); atomicAdd(&ws[WS_CACC + bi0], 1.0f);
        atomicAdd(&ws[WS_EACC + bi1], bv1); atomicAdd(&ws[WS_CACC + bi1], 1.0f);
        atomicAdd(&ws[WS_EACC + bi2], bv2); atomicAdd(&ws[WS_CACC + bi2], 1.0f);
        atomicAdd(&ws[WS_EACC + bi3], bv3); atomicAdd(&ws[WS_CACC + bi3], 1.0f);
    }
    __syncthreads();

    // w[t][k*16+b] = R[t][e*16+b] * uscale[e*16+b]
    {
        const int t = tid >> 6, slot = tid & 63;
        const int e = sidx[t][slot >> 4];
        const int c = (e << 4) + (slot & 15);
        w[t][slot] = ws[WS_R + (size_t)(t0 + t) * NC + c] * ws[WS_USCALE + c];
    }
    __syncthreads();

#pragma unroll
    for (int t = 0; t < TTB; ++t) {
#pragma unroll
        for (int dh = 0; dh < 2; ++dh) {
            const int d = (dh << 8) + tid;
            float acc4[KSEL];
#pragma unroll
            for (int k = 0; k < KSEL; ++k) {
                const int e = sidx[t][k];
                const float4* Up = (const float4*)(U + (size_t)e * (D * B) + (size_t)d * B);
                float4 u0 = Up[0], u1 = Up[1], u2 = Up[2], u3 = Up[3];
                const float* wp = &w[t][k << 4];
                float s;
                s  = u0.x * wp[0]  + u0.y * wp[1]  + u0.z * wp[2]  + u0.w * wp[3];
                s += u1.x * wp[4]  + u1.y * wp[5]  + u1.z * wp[6]  + u1.w * wp[7];
                s += u2.x * wp[8]  + u2.y * wp[9]  + u2.z * wp[10] + u2.w * wp[11];
                s += u3.x * wp[12] + u3.y * wp[13] + u3.z * wp[14] + u3.w * wp[15];
                acc4[k] = s;
            }
            out[(size_t)(t0 + t) * D + d] =
                x[(size_t)(t0 + t) * D + d] + ((acc4[0] + acc4[1]) + (acc4[2] + acc4[3]));
        }
    }
}

// Gram |A^T A - I| sum over upper-triangle 64x64 tiles (x2 off-diagonal).
__launch_bounds__(256)
__global__ void gram_kernel(const float* __restrict__ A,
                            const float* __restrict__ scales,
                            float* __restrict__ sum_out,
                            int mode) {
    int bi = blockIdx.x, bj = blockIdx.y;
    if (bi > bj) return;

    __shared__ __attribute__((aligned(16))) float As[32][64];
    __shared__ __attribute__((aligned(16))) float Bs[32][64];

    const int tid = threadIdx.x;
    const int r0 = (tid & 15) << 2;
    const int c0 = (tid >> 4) << 2;

    float acc[4][4];
#pragma unroll
    for (int ii = 0; ii < 4; ++ii)
#pragma unroll
        for (int jj = 0; jj < 4; ++jj) acc[ii][jj] = 0.0f;

    const int li = tid << 3;
    const int dd = li >> 6;
    const int cc = li & 63;

    float4 ra0, ra1, rb0, rb1;
    auto load_regs = [&](int d0) {
        if (mode == 0) {
            const float* pa = A + (size_t)(d0 + dd) * NC + bi * 64 + cc;
            ra0 = *(const float4*)(pa);
            ra1 = *(const float4*)(pa + 4);
            const float* pb = A + (size_t)(d0 + dd) * NC + bj * 64 + cc;
            rb0 = *(const float4*)(pb);
            rb1 = *(const float4*)(pb + 4);
        } else {
            int colA = bi * 64 + cc;
            const float* pa = A + (size_t)(colA >> 4) * (D * B) + (size_t)(d0 + dd) * B + (colA & 15);
            ra0 = *(const float4*)(pa);
            ra1 = *(const float4*)(pa + 4);
            int colB = bj * 64 + cc;
            const float* pb = A + (size_t)(colB >> 4) * (D * B) + (size_t)(d0 + dd) * B + (colB & 15);
            rb0 = *(const float4*)(pb);
            rb1 = *(const float4*)(pb + 4);
        }
    };

    load_regs(0);
    for (int d0 = 0; d0 < D; d0 += 32) {
        *(float4*)&As[dd][cc]     = ra0;
        *(float4*)&As[dd][cc + 4] = ra1;
        *(float4*)&Bs[dd][cc]     = rb0;
        *(float4*)&Bs[dd][cc + 4] = rb1;
        __syncthreads();
        if (d0 + 32 < D) load_regs(d0 + 32);
#pragma unroll
        for (int dd2 = 0; dd2 < 32; ++dd2) {
            float4 a4 = *(const float4*)&As[dd2][r0];
            float4 b4 = *(const float4*)&Bs[dd2][c0];
            float ar[4] = {a4.x, a4.y, a4.z, a4.w};
            float br[4] = {b4.x, b4.y, b4.z, b4.w};
#pragma unroll
            for (int ii = 0; ii < 4; ++ii)
#pragma unroll
                for (int jj = 0; jj < 4; ++jj)
                    acc[ii][jj] = fmaf(ar[ii], br[jj], acc[ii][jj]);
        }
        __syncthreads();
    }

    const int gi0 = bi * 64 + r0, gj0 = bj * 64 + c0;
    float si[4], sj[4];
#pragma unroll
    for (int ii = 0; ii < 4; ++ii) { si[ii] = scales[gi0 + ii]; sj[ii] = scales[gj0 + ii]; }

    float local = 0.0f;
#pragma unroll
    for (int ii = 0; ii < 4; ++ii)
#pragma unroll
        for (int jj = 0; jj < 4; ++jj) {
            float g = acc[ii][jj] * si[ii] * sj[jj];
            if (gi0 + ii == gj0 + jj) g -= 1.0f;
            local += fabsf(g);
        }
    if (bi != bj) local *= 2.0f;

#pragma unroll
    for (int off = 32; off > 0; off >>= 1) local += __shfl_down(local, off);
    __shared__ float red[4];
    if ((tid & 63) == 0) red[tid >> 6] = local;
    __syncthreads();
    if (tid == 0) atomicAdd(sum_out, (red[0] + red[1]) + (red[2] + red[3]));
}

__global__ void finalize_kernel(const float* __restrict__ ws, float* __restrict__ out) {
    const int m = threadIdx.x;   // 128 threads
    float e = ws[WS_EACC + m] * (1.0f / (float)NTOK);
    float c = ws[WS_CACC + m] * (1.0f / (float)NTOK);

    float s = e;
#pragma unroll
    for (int off = 32; off > 0; off >>= 1) s += __shfl_down(s, off);
    __shared__ float sh[2];
    if ((m & 63) == 0) sh[m >> 6] = s;
    __syncthreads();
    float total = sh[0] + sh[1];
    float total_energy = fmaxf(total, 1e-12f);

    out[OUT_EPE + m] = e;
    out[OUT_RE + m] = e / total_energy;
    out[OUT_SR + m] = c;
    if (m == 0) {
        out[OUT_TE] = total_energy;
        float inv_n2 = 1.0f / ((float)NC * (float)NC);
        float sqrtD = sqrtf((float)D);
        float vpen = ws[WS_VSUM] * inv_n2 * sqrtD;
        float upen = ws[WS_USUM] * inv_n2 * sqrtD;
        out[OUT_VPEN] = vpen;
        out[OUT_UPEN] = upen;
        out[OUT_AUX] = 0.01f * vpen - total_energy;
    }
}

extern "C" void kernel_launch(void* const* d_in, const int* in_sizes, int n_in,
                              void* d_out, int out_size, void* d_ws, size_t ws_size,
                              hipStream_t stream) {
    const float* x  = (const float*)d_in[0];
    const float* V  = (const float*)d_in[1];
    const float* U  = (const float*)d_in[2];
    const float* us = (const float*)d_in[3];
    float* out = (float*)d_out;
    float* ws  = (float*)d_ws;

    init_ws_kernel<<<2, 256, 0, stream>>>(ws);
    scales_kernel<<<160, 256, 0, stream>>>(V, U, us, ws);
    gemm_kernel<<<dim3(32, 16), 256, 0, stream>>>(x, V, ws);
    topk_write_kernel<<<NTOK / TTB, 256, 0, stream>>>(x, U, ws, out);
    gram_kernel<<<dim3(32, 32), 256, 0, stream>>>(V, ws + WS_VSCALE, ws + WS_VSUM, 0);
    gram_kernel<<<dim3(32, 32), 256, 0, stream>>>(U, ws + WS_USCALE, ws + WS_USUM, 1);
    finalize_kernel<<<1, 128, 0, stream>>>(ws, out);
}

// Round 4
// 381.625 us; speedup vs baseline: 1.4428x; 1.1180x over previous
//
#include <hip/hip_runtime.h>
#include <math.h>

#define D 512
#define M 128
#define B 16
#define KSEL 4
#define NC 2048           // M*B
#define NTOK 4096         // 2*2048
#define TTB 4             // tokens per block in topk/write kernel

typedef unsigned short ushort;
typedef unsigned int uint;
typedef __attribute__((ext_vector_type(8))) short short8;   // 8 bf16 (4 VGPRs)
typedef __attribute__((ext_vector_type(4))) float floatx4;  // 4 fp32 acc

// ws layout (float indices)
#define WS_EACC   0       // [128]
#define WS_CACC   128     // [128]
#define WS_VSUM   256     // [1]
#define WS_USUM   257     // [1]
#define WS_VSCALE 512     // [2048] 1/||V col||
#define WS_USCALE 2560    // [2048] tanh(us)/||U col||
#define WS_E_F    4608    // [NTOK*M] fp32 energies, 2 MB
#define WS_RBF_F  528896  // R bf16 [NTOK][NC] = 2097152 float slots (16 MB)
#define WS_XH_F   2626048 // xh bf16 [NTOK][D]  (4 MB)
#define WS_XL_F   3674624 // xl bf16
#define WS_VHT_F  4723200 // VhT bf16 [NC][D]   (2 MB)
#define WS_VLT_F  5247488
#define WS_UHT_F  5771776 // UhT bf16 [NC][D] (col = m*16+b)
#define WS_ULT_F  6296064 // end: 6820352 floats = 27.3 MB

// out layout (floats)
#define OUT_TE   2097152
#define OUT_EPE  2097153
#define OUT_RE   2097281
#define OUT_SR   2097409
#define OUT_VPEN 2097537
#define OUT_UPEN 2097538
#define OUT_AUX  2097539

__device__ __forceinline__ ushort f2bf(float f) {   // RNE
    union { float f; uint u; } a; a.f = f;
    uint u = a.u;
    u += 0x7fffu + ((u >> 16) & 1u);
    return (ushort)(u >> 16);
}
__device__ __forceinline__ float bf2f(ushort h) {
    union { uint u; float f; } a; a.u = ((uint)h) << 16;
    return a.f;
}

__global__ void init_ws_kernel(float* __restrict__ ws) {
    int i = blockIdx.x * 256 + threadIdx.x;
    if (i < 512) ws[i] = 0.0f;
}

// x (fp32, [4096][512]) -> xh + xl bf16 (same layout). 8 elems/thread.
__global__ void convert_x(const float* __restrict__ x, ushort* __restrict__ xh,
                          ushort* __restrict__ xl) {
    const int idx = (blockIdx.x * 256 + threadIdx.x) * 8;
    float4 v0 = *(const float4*)(x + idx);
    float4 v1 = *(const float4*)(x + idx + 4);
    float vv[8] = {v0.x, v0.y, v0.z, v0.w, v1.x, v1.y, v1.z, v1.w};
    union { ushort u[8]; uint4 q; } H, L;
#pragma unroll
    for (int j = 0; j < 8; ++j) {
        ushort h = f2bf(vv[j]);
        H.u[j] = h;
        L.u[j] = f2bf(vv[j] - bf2f(h));
    }
    *(uint4*)(xh + idx) = H.q;
    *(uint4*)(xl + idx) = L.q;
}

// V [d][col] fp32 -> VhT/VlT [col][d] bf16 via LDS transpose. 64x64 tiles.
__global__ void convert_VT(const float* __restrict__ V, ushort* __restrict__ vht,
                           ushort* __restrict__ vlt) {
    __shared__ float ts[64][65];
    const int tid = threadIdx.x;
    const int col0 = blockIdx.x * 64;
    const int d0 = blockIdx.y * 64;
#pragma unroll
    for (int i = 0; i < 16; ++i) {
        int idx = i * 256 + tid;
        int r = idx >> 6, c = idx & 63;          // r = d-local, c = col-local
        ts[r][c] = V[(size_t)(d0 + r) * NC + col0 + c];
    }
    __syncthreads();
#pragma unroll
    for (int i = 0; i < 16; ++i) {
        int idx = i * 256 + tid;
        int c2 = idx >> 6, d2 = idx & 63;        // write d-contiguous
        float v = ts[d2][c2];
        ushort h = f2bf(v);
        vht[(size_t)(col0 + c2) * D + d0 + d2] = h;
        vlt[(size_t)(col0 + c2) * D + d0 + d2] = f2bf(v - bf2f(h));
    }
}

// U (m, D, b) fp32 -> UhT/UlT [col=m*16+b][d] bf16. One block per expert m.
__global__ void convert_UT(const float* __restrict__ U, ushort* __restrict__ uht,
                           ushort* __restrict__ ult) {
    __shared__ float ts[16][129];
    const int tid = threadIdx.x;
    const int m = blockIdx.x;
    for (int d0 = 0; d0 < D; d0 += 128) {
        __syncthreads();
#pragma unroll
        for (int i = 0; i < 8; ++i) {
            int idx = i * 256 + tid;
            int d2 = idx >> 4, b2 = idx & 15;
            ts[b2][d2] = U[(size_t)m * (D * B) + (size_t)(d0 + d2) * B + b2];
        }
        __syncthreads();
#pragma unroll
        for (int i = 0; i < 8; ++i) {
            int idx = i * 256 + tid;
            int b3 = idx >> 7, d3 = idx & 127;
            float v = ts[b3][d3];
            ushort h = f2bf(v);
            uht[(size_t)((m << 4) + b3) * D + d0 + d3] = h;
            ult[(size_t)((m << 4) + b3) * D + d0 + d3] = f2bf(v - bf2f(h));
        }
    }
}

// Coalesced norms. blocks 0..31: V cols (64 per block). blocks 32..159: U expert m.
__global__ void scales_kernel(const float* __restrict__ V,
                              const float* __restrict__ U,
                              const float* __restrict__ us_in,
                              float* __restrict__ ws) {
    const int bx = blockIdx.x;
    const int tid = threadIdx.x;
    if (bx < 32) {
        const int c = bx * 64 + (tid & 63);
        const int dg = tid >> 6;
        float s = 0.0f;
        for (int d = dg; d < D; d += 4) {
            float v = V[(size_t)d * NC + c];
            s = fmaf(v, v, s);
        }
        __shared__ float sh[4][64];
        sh[dg][tid & 63] = s;
        __syncthreads();
        if (tid < 64) {
            float t = (sh[0][tid] + sh[1][tid]) + (sh[2][tid] + sh[3][tid]);
            ws[WS_VSCALE + bx * 64 + tid] = 1.0f / sqrtf(t);
        }
    } else {
        const int m = bx - 32;
        const float* p = U + (size_t)m * (D * B);
        float s = 0.0f;
        for (int i = tid; i < D * B; i += 256) {
            float v = p[i];
            s = fmaf(v, v, s);
        }
        __shared__ float sh2[256];
        sh2[tid] = s;
        __syncthreads();
        if (tid < 16) {
            float t = 0.0f;
#pragma unroll
            for (int j = 0; j < 16; ++j) t += sh2[tid + (j << 4)];
            ws[WS_USCALE + (m << 4) + tid] = tanhf(us_in[(m << 4) + tid]) / sqrtf(t);
        }
    }
}

// MFMA split-bf16 GEMM: R = (x @ V)*vscale (bf16 out) + exact-ish E energies.
// Block: 128 tok x 128 col, 4 waves (2x2 of 64x64). No LDS; operands stream
// from L2-resident d-contiguous bf16 arrays. 3 passes: AhBh + AhBl + AlBh.
__launch_bounds__(256)
__global__ void mfma_gemm(const ushort* __restrict__ xh, const ushort* __restrict__ xl,
                          const ushort* __restrict__ vht, const ushort* __restrict__ vlt,
                          float* __restrict__ ws, ushort* __restrict__ rbf) {
    const int tid = threadIdx.x, lane = tid & 63, w = tid >> 6;
    const int wr = w >> 1, wc = w & 1;
    const int tok0 = blockIdx.x * 128 + wr * 64;
    const int col0 = blockIdx.y * 128 + wc * 64;
    const int r15 = lane & 15, q = lane >> 4;

    size_t aoff[4], boff[4];
#pragma unroll
    for (int s = 0; s < 4; ++s) {
        aoff[s] = (size_t)(tok0 + s * 16 + r15) * D + q * 8;
        boff[s] = (size_t)(col0 + s * 16 + r15) * D + q * 8;
    }

    floatx4 acc[4][4];
#pragma unroll
    for (int i = 0; i < 4; ++i)
#pragma unroll
        for (int j = 0; j < 4; ++j) acc[i][j] = (floatx4){0.f, 0.f, 0.f, 0.f};

    short8 Ah[2][4], Al[2][4], Bh[2][4], Bl[2][4];
#pragma unroll
    for (int s = 0; s < 4; ++s) {
        Ah[0][s] = *(const short8*)(xh + aoff[s]);
        Al[0][s] = *(const short8*)(xl + aoff[s]);
        Bh[0][s] = *(const short8*)(vht + boff[s]);
        Bl[0][s] = *(const short8*)(vlt + boff[s]);
    }

#pragma unroll
    for (int kc = 0; kc < 16; ++kc) {
        const int cur = kc & 1, nxt = cur ^ 1;
        if (kc < 15) {
            const int d0 = (kc + 1) * 32;
#pragma unroll
            for (int s = 0; s < 4; ++s) {
                Ah[nxt][s] = *(const short8*)(xh + aoff[s] + d0);
                Al[nxt][s] = *(const short8*)(xl + aoff[s] + d0);
                Bh[nxt][s] = *(const short8*)(vht + boff[s] + d0);
                Bl[nxt][s] = *(const short8*)(vlt + boff[s] + d0);
            }
        }
#pragma unroll
        for (int st = 0; st < 4; ++st)
#pragma unroll
            for (int sc = 0; sc < 4; ++sc) {
                acc[st][sc] = __builtin_amdgcn_mfma_f32_16x16x32_bf16(Ah[cur][st], Bh[cur][sc], acc[st][sc], 0, 0, 0);
                acc[st][sc] = __builtin_amdgcn_mfma_f32_16x16x32_bf16(Ah[cur][st], Bl[cur][sc], acc[st][sc], 0, 0, 0);
                acc[st][sc] = __builtin_amdgcn_mfma_f32_16x16x32_bf16(Al[cur][st], Bh[cur][sc], acc[st][sc], 0, 0, 0);
            }
    }

    // Epilogue: fold vscale; store bf16 R; reduce energies per (tok, expert).
#pragma unroll
    for (int sc = 0; sc < 4; ++sc) {
        const int colg = col0 + sc * 16 + r15;
        const float vs = ws[WS_VSCALE + colg];
        const int ex = (col0 >> 4) + sc;
#pragma unroll
        for (int st = 0; st < 4; ++st) {
            const int rowb = tok0 + st * 16 + q * 4;
            float r0 = acc[st][sc][0] * vs;
            float r1 = acc[st][sc][1] * vs;
            float r2 = acc[st][sc][2] * vs;
            float r3 = acc[st][sc][3] * vs;
            rbf[(size_t)(rowb + 0) * NC + colg] = f2bf(r0);
            rbf[(size_t)(rowb + 1) * NC + colg] = f2bf(r1);
            rbf[(size_t)(rowb + 2) * NC + colg] = f2bf(r2);
            rbf[(size_t)(rowb + 3) * NC + colg] = f2bf(r3);
            float e0 = r0 * r0, e1 = r1 * r1, e2 = r2 * r2, e3 = r3 * r3;
#pragma unroll
            for (int mk = 1; mk < 16; mk <<= 1) {
                e0 += __shfl_xor(e0, mk);
                e1 += __shfl_xor(e1, mk);
                e2 += __shfl_xor(e2, mk);
                e3 += __shfl_xor(e3, mk);
            }
            if (r15 == 0) {
                float* ep = ws + WS_E_F + (size_t)rowb * M + ex;
                ep[0] = e0; ep[M] = e1; ep[2 * M] = e2; ep[3 * M] = e3;
            }
        }
    }
}

// MFMA split-bf16 Gram: sum |diag(s) A^T A diag(s) - I| over 64x64 tiles, bi<=bj.
__launch_bounds__(256)
__global__ void mfma_gram(const ushort* __restrict__ aht, const ushort* __restrict__ alt,
                          const float* __restrict__ scales, float* __restrict__ sum_out) {
    const int bi = blockIdx.x, bj = blockIdx.y;
    if (bi > bj) return;
    const int tid = threadIdx.x, lane = tid & 63, w = tid >> 6;
    const int wr = w >> 1, wc = w & 1;
    const int row0 = bi * 64 + wr * 32;
    const int colb0 = bj * 64 + wc * 32;
    const int r15 = lane & 15, q = lane >> 4;

    size_t aoff[2], boff[2];
#pragma unroll
    for (int s = 0; s < 2; ++s) {
        aoff[s] = (size_t)(row0 + s * 16 + r15) * D + q * 8;
        boff[s] = (size_t)(colb0 + s * 16 + r15) * D + q * 8;
    }

    floatx4 acc[2][2];
#pragma unroll
    for (int i = 0; i < 2; ++i)
#pragma unroll
        for (int j = 0; j < 2; ++j) acc[i][j] = (floatx4){0.f, 0.f, 0.f, 0.f};

    short8 Ah[2][2], Al[2][2], Bh[2][2], Bl[2][2];
#pragma unroll
    for (int s = 0; s < 2; ++s) {
        Ah[0][s] = *(const short8*)(aht + aoff[s]);
        Al[0][s] = *(const short8*)(alt + aoff[s]);
        Bh[0][s] = *(const short8*)(aht + boff[s]);
        Bl[0][s] = *(const short8*)(alt + boff[s]);
    }
#pragma unroll
    for (int kc = 0; kc < 16; ++kc) {
        const int cur = kc & 1, nxt = cur ^ 1;
        if (kc < 15) {
            const int d0 = (kc + 1) * 32;
#pragma unroll
            for (int s = 0; s < 2; ++s) {
                Ah[nxt][s] = *(const short8*)(aht + aoff[s] + d0);
                Al[nxt][s] = *(const short8*)(alt + aoff[s] + d0);
                Bh[nxt][s] = *(const short8*)(aht + boff[s] + d0);
                Bl[nxt][s] = *(const short8*)(alt + boff[s] + d0);
            }
        }
#pragma unroll
        for (int si = 0; si < 2; ++si)
#pragma unroll
            for (int sj = 0; sj < 2; ++sj) {
                acc[si][sj] = __builtin_amdgcn_mfma_f32_16x16x32_bf16(Ah[cur][si], Bh[cur][sj], acc[si][sj], 0, 0, 0);
                acc[si][sj] = __builtin_amdgcn_mfma_f32_16x16x32_bf16(Ah[cur][si], Bl[cur][sj], acc[si][sj], 0, 0, 0);
                acc[si][sj] = __builtin_amdgcn_mfma_f32_16x16x32_bf16(Al[cur][si], Bh[cur][sj], acc[si][sj], 0, 0, 0);
            }
    }

    float local = 0.0f;
#pragma unroll
    for (int si = 0; si < 2; ++si)
#pragma unroll
        for (int sj = 0; sj < 2; ++sj) {
            const int colg = colb0 + sj * 16 + r15;
            const float scj = scales[colg];
#pragma unroll
            for (int reg = 0; reg < 4; ++reg) {
                const int rowg = row0 + si * 16 + q * 4 + reg;
                float g = acc[si][sj][reg] * scales[rowg] * scj;
                if (rowg == colg) g -= 1.0f;
                local += fabsf(g);
            }
        }
    if (bi < bj) local *= 2.0f;

#pragma unroll
    for (int mk = 1; mk < 64; mk <<= 1) local += __shfl_xor(local, mk);
    __shared__ float red[4];
    if (lane == 0) red[w] = local;
    __syncthreads();
    if (tid == 0) atomicAdd(sum_out, (red[0] + red[1]) + (red[2] + red[3]));
}

// top-4 (exact jax semantics) + aux atomics + U-gather writes + residual
__launch_bounds__(256)
__global__ void topk_write_kernel(const float* __restrict__ x,
                                  const float* __restrict__ U,
                                  float* __restrict__ ws,
                                  const ushort* __restrict__ rbf,
                                  float* __restrict__ out) {
    __shared__ float en[TTB][M];
    __shared__ int   sidx[TTB][KSEL];
    __shared__ float w[TTB][64];

    const int tid = threadIdx.x;
    const int t0 = blockIdx.x * TTB;

#pragma unroll
    for (int i = 0; i < (TTB * M) / 256; ++i)
        ((float*)en)[i * 256 + tid] = ws[WS_E_F + (size_t)t0 * M + i * 256 + tid];
    __syncthreads();

    if (tid < TTB) {
        float bv0 = -1e30f, bv1 = -1e30f, bv2 = -1e30f, bv3 = -1e30f;
        int bi0 = 0, bi1 = 0, bi2 = 0, bi3 = 0;
        for (int m = 0; m < M; ++m) {
            float v = en[tid][m];
            if (v > bv3) {
                if (v > bv0) {
                    bv3 = bv2; bi3 = bi2; bv2 = bv1; bi2 = bi1; bv1 = bv0; bi1 = bi0;
                    bv0 = v; bi0 = m;
                } else if (v > bv1) {
                    bv3 = bv2; bi3 = bi2; bv2 = bv1; bi2 = bi1;
                    bv1 = v; bi1 = m;
                } else if (v > bv2) {
                    bv3 = bv2; bi3 = bi2;
                    bv2 = v; bi2 = m;
                } else {
                    bv3 = v; bi3 = m;
                }
            }
        }
        sidx[tid][0] = bi0; sidx[tid][1] = bi1; sidx[tid][2] = bi2; sidx[tid][3] = bi3;
        atomicAdd(&ws[WS_EACC + bi0], bv0); atomicAdd(&ws[WS_CACC + bi0], 1.0f);
        atomicAdd(&ws[WS_EACC + bi1], bv1); atomicAdd(&ws[WS_CACC + bi1], 1.0f);
        atomicAdd(&ws[WS_EACC + bi2], bv2); atomicAdd(&ws[WS_CACC + bi2], 1.0f);
        atomicAdd(&ws[WS_EACC + bi3], bv3); atomicAdd(&ws[WS_CACC + bi3], 1.0f);
    }
    __syncthreads();

    {
        const int t = tid >> 6, slot = tid & 63;
        const int e = sidx[t][slot >> 4];
        const int c = (e << 4) + (slot & 15);
        w[t][slot] = bf2f(rbf[(size_t)(t0 + t) * NC + c]) * ws[WS_USCALE + c];
    }
    __syncthreads();

#pragma unroll
    for (int t = 0; t < TTB; ++t) {
#pragma unroll
        for (int dh = 0; dh < 2; ++dh) {
            const int d = (dh << 8) + tid;
            float acc4[KSEL];
#pragma unroll
            for (int k = 0; k < KSEL; ++k) {
                const int e = sidx[t][k];
                const float4* Up = (const float4*)(U + (size_t)e * (D * B) + (size_t)d * B);
                float4 u0 = Up[0], u1 = Up[1], u2 = Up[2], u3 = Up[3];
                const float* wp = &w[t][k << 4];
                float s;
                s  = u0.x * wp[0]  + u0.y * wp[1]  + u0.z * wp[2]  + u0.w * wp[3];
                s += u1.x * wp[4]  + u1.y * wp[5]  + u1.z * wp[6]  + u1.w * wp[7];
                s += u2.x * wp[8]  + u2.y * wp[9]  + u2.z * wp[10] + u2.w * wp[11];
                s += u3.x * wp[12] + u3.y * wp[13] + u3.z * wp[14] + u3.w * wp[15];
                acc4[k] = s;
            }
            out[(size_t)(t0 + t) * D + d] =
                x[(size_t)(t0 + t) * D + d] + ((acc4[0] + acc4[1]) + (acc4[2] + acc4[3]));
        }
    }
}

__global__ void finalize_kernel(const float* __restrict__ ws, float* __restrict__ out) {
    const int m = threadIdx.x;   // 128 threads
    float e = ws[WS_EACC + m] * (1.0f / (float)NTOK);
    float c = ws[WS_CACC + m] * (1.0f / (float)NTOK);

    float s = e;
#pragma unroll
    for (int off = 32; off > 0; off >>= 1) s += __shfl_down(s, off);
    __shared__ float sh[2];
    if ((m & 63) == 0) sh[m >> 6] = s;
    __syncthreads();
    float total = sh[0] + sh[1];
    float total_energy = fmaxf(total, 1e-12f);

    out[OUT_EPE + m] = e;
    out[OUT_RE + m] = e / total_energy;
    out[OUT_SR + m] = c;
    if (m == 0) {
        out[OUT_TE] = total_energy;
        float inv_n2 = 1.0f / ((float)NC * (float)NC);
        float sqrtD = sqrtf((float)D);
        float vpen = ws[WS_VSUM] * inv_n2 * sqrtD;
        float upen = ws[WS_USUM] * inv_n2 * sqrtD;
        out[OUT_VPEN] = vpen;
        out[OUT_UPEN] = upen;
        out[OUT_AUX] = 0.01f * vpen - total_energy;
    }
}

extern "C" void kernel_launch(void* const* d_in, const int* in_sizes, int n_in,
                              void* d_out, int out_size, void* d_ws, size_t ws_size,
                              hipStream_t stream) {
    const float* x  = (const float*)d_in[0];
    const float* V  = (const float*)d_in[1];
    const float* U  = (const float*)d_in[2];
    const float* us = (const float*)d_in[3];
    float* out = (float*)d_out;
    float* ws  = (float*)d_ws;

    ushort* xh  = (ushort*)(ws + WS_XH_F);
    ushort* xl  = (ushort*)(ws + WS_XL_F);
    ushort* vht = (ushort*)(ws + WS_VHT_F);
    ushort* vlt = (ushort*)(ws + WS_VLT_F);
    ushort* uht = (ushort*)(ws + WS_UHT_F);
    ushort* ult = (ushort*)(ws + WS_ULT_F);
    ushort* rbf = (ushort*)(ws + WS_RBF_F);

    init_ws_kernel<<<2, 256, 0, stream>>>(ws);
    convert_x<<<1024, 256, 0, stream>>>(x, xh, xl);
    convert_VT<<<dim3(32, 8), 256, 0, stream>>>(V, vht, vlt);
    convert_UT<<<128, 256, 0, stream>>>(U, uht, ult);
    scales_kernel<<<160, 256, 0, stream>>>(V, U, us, ws);
    mfma_gemm<<<dim3(32, 16), 256, 0, stream>>>(xh, xl, vht, vlt, ws, rbf);
    topk_write_kernel<<<NTOK / TTB, 256, 0, stream>>>(x, U, ws, rbf, out);
    mfma_gram<<<dim3(32, 32), 256, 0, stream>>>(vht, vlt, ws + WS_VSCALE, ws + WS_VSUM);
    mfma_gram<<<dim3(32, 32), 256, 0, stream>>>(uht, ult, ws + WS_USCALE, ws + WS_USUM);
    finalize_kernel<<<1, 128, 0, stream>>>(ws, out);
}

// Round 5
// 371.702 us; speedup vs baseline: 1.4813x; 1.0267x over previous
//
#include <hip/hip_runtime.h>
#include <math.h>

#define D 512
#define M 128
#define B 16
#define KSEL 4
#define NC 2048           // M*B
#define NTOK 4096         // 2*2048
#define TTB 4             // tokens per block in topk kernel

typedef unsigned short ushort;
typedef unsigned int uint;
typedef __attribute__((ext_vector_type(8))) short short8;   // 8 bf16 (4 VGPRs)
typedef __attribute__((ext_vector_type(4))) float floatx4;  // 4 fp32 acc

// ws layout (float indices)
#define WS_EACC   0       // [128]
#define WS_CACC   128     // [128]
#define WS_VSUM   256     // [1]
#define WS_USUM   257     // [1]
// int counters at int-index 258..385 (inside the zeroed first 512 floats)
#define WS_CNT_I  258
#define WS_VSCALE 512     // [2048] 1/||V col||
#define WS_USCALE 2560    // [2048] tanh(us)/||U col||
#define WS_E_F    4608    // [NTOK*M] fp32 energies, 2 MB
#define WS_RBF_F  528896  // R bf16 [NTOK][NC] = 2097152 float slots (16 MB)
#define WS_XH_F   2626048 // xh bf16 [NTOK][D]  (4 MB)
#define WS_XL_F   3674624 // xl bf16
#define WS_VHT_F  4723200 // VhT bf16 [NC][D]   (2 MB)
#define WS_VLT_F  5247488
#define WS_UHT_F  5771776 // UhT bf16 [NC][D] (col = m*16+b)
#define WS_ULT_F  6296064
#define WS_LIST_F 6820352 // int [128][4096] per-expert token lists (2 MB)
                          // end: 7344640 floats = 29.4 MB (proven ws >= 35.7 MB)

// out layout (floats)
#define OUT_TE   2097152
#define OUT_EPE  2097153
#define OUT_RE   2097281
#define OUT_SR   2097409
#define OUT_VPEN 2097537
#define OUT_UPEN 2097538
#define OUT_AUX  2097539

__device__ __forceinline__ ushort f2bf(float f) {   // RNE
    union { float f; uint u; } a; a.f = f;
    uint u = a.u;
    u += 0x7fffu + ((u >> 16) & 1u);
    return (ushort)(u >> 16);
}
__device__ __forceinline__ float bf2f(ushort h) {
    union { uint u; float f; } a; a.u = ((uint)h) << 16;
    return a.f;
}

__global__ void init_ws_kernel(float* __restrict__ ws) {
    int i = blockIdx.x * 256 + threadIdx.x;
    if (i < 512) ws[i] = 0.0f;
}

// x (fp32, [4096][512]) -> xh + xl bf16 (same layout). 8 elems/thread.
__global__ void convert_x(const float* __restrict__ x, ushort* __restrict__ xh,
                          ushort* __restrict__ xl) {
    const int idx = (blockIdx.x * 256 + threadIdx.x) * 8;
    float4 v0 = *(const float4*)(x + idx);
    float4 v1 = *(const float4*)(x + idx + 4);
    float vv[8] = {v0.x, v0.y, v0.z, v0.w, v1.x, v1.y, v1.z, v1.w};
    union { ushort u[8]; uint4 q; } H, L;
#pragma unroll
    for (int j = 0; j < 8; ++j) {
        ushort h = f2bf(vv[j]);
        H.u[j] = h;
        L.u[j] = f2bf(vv[j] - bf2f(h));
    }
    *(uint4*)(xh + idx) = H.q;
    *(uint4*)(xl + idx) = L.q;
}

// V [d][col] fp32 -> VhT/VlT [col][d] bf16 via LDS transpose. 64x64 tiles.
__global__ void convert_VT(const float* __restrict__ V, ushort* __restrict__ vht,
                           ushort* __restrict__ vlt) {
    __shared__ float ts[64][65];
    const int tid = threadIdx.x;
    const int col0 = blockIdx.x * 64;
    const int d0 = blockIdx.y * 64;
#pragma unroll
    for (int i = 0; i < 16; ++i) {
        int idx = i * 256 + tid;
        int r = idx >> 6, c = idx & 63;
        ts[r][c] = V[(size_t)(d0 + r) * NC + col0 + c];
    }
    __syncthreads();
#pragma unroll
    for (int i = 0; i < 16; ++i) {
        int idx = i * 256 + tid;
        int c2 = idx >> 6, d2 = idx & 63;
        float v = ts[d2][c2];
        ushort h = f2bf(v);
        vht[(size_t)(col0 + c2) * D + d0 + d2] = h;
        vlt[(size_t)(col0 + c2) * D + d0 + d2] = f2bf(v - bf2f(h));
    }
}

// U (m, D, b) fp32 -> UhT/UlT [col=m*16+b][d] bf16. One block per expert m.
__global__ void convert_UT(const float* __restrict__ U, ushort* __restrict__ uht,
                           ushort* __restrict__ ult) {
    __shared__ float ts[16][129];
    const int tid = threadIdx.x;
    const int m = blockIdx.x;
    for (int d0 = 0; d0 < D; d0 += 128) {
        __syncthreads();
#pragma unroll
        for (int i = 0; i < 8; ++i) {
            int idx = i * 256 + tid;
            int d2 = idx >> 4, b2 = idx & 15;
            ts[b2][d2] = U[(size_t)m * (D * B) + (size_t)(d0 + d2) * B + b2];
        }
        __syncthreads();
#pragma unroll
        for (int i = 0; i < 8; ++i) {
            int idx = i * 256 + tid;
            int b3 = idx >> 7, d3 = idx & 127;
            float v = ts[b3][d3];
            ushort h = f2bf(v);
            uht[(size_t)((m << 4) + b3) * D + d0 + d3] = h;
            ult[(size_t)((m << 4) + b3) * D + d0 + d3] = f2bf(v - bf2f(h));
        }
    }
}

// Coalesced norms. blocks 0..31: V cols (64 per block). blocks 32..159: U expert m.
__global__ void scales_kernel(const float* __restrict__ V,
                              const float* __restrict__ U,
                              const float* __restrict__ us_in,
                              float* __restrict__ ws) {
    const int bx = blockIdx.x;
    const int tid = threadIdx.x;
    if (bx < 32) {
        const int c = bx * 64 + (tid & 63);
        const int dg = tid >> 6;
        float s = 0.0f;
        for (int d = dg; d < D; d += 4) {
            float v = V[(size_t)d * NC + c];
            s = fmaf(v, v, s);
        }
        __shared__ float sh[4][64];
        sh[dg][tid & 63] = s;
        __syncthreads();
        if (tid < 64) {
            float t = (sh[0][tid] + sh[1][tid]) + (sh[2][tid] + sh[3][tid]);
            ws[WS_VSCALE + bx * 64 + tid] = 1.0f / sqrtf(t);
        }
    } else {
        const int m = bx - 32;
        const float* p = U + (size_t)m * (D * B);
        float s = 0.0f;
        for (int i = tid; i < D * B; i += 256) {
            float v = p[i];
            s = fmaf(v, v, s);
        }
        __shared__ float sh2[256];
        sh2[tid] = s;
        __syncthreads();
        if (tid < 16) {
            float t = 0.0f;
#pragma unroll
            for (int j = 0; j < 16; ++j) t += sh2[tid + (j << 4)];
            ws[WS_USCALE + (m << 4) + tid] = tanhf(us_in[(m << 4) + tid]) / sqrtf(t);
        }
    }
}

// MFMA split-bf16 GEMM: R = (x @ V)*vscale (bf16 out) + E energies.
__launch_bounds__(256)
__global__ void mfma_gemm(const ushort* __restrict__ xh, const ushort* __restrict__ xl,
                          const ushort* __restrict__ vht, const ushort* __restrict__ vlt,
                          float* __restrict__ ws, ushort* __restrict__ rbf) {
    const int tid = threadIdx.x, lane = tid & 63, w = tid >> 6;
    const int wr = w >> 1, wc = w & 1;
    const int tok0 = blockIdx.x * 128 + wr * 64;
    const int col0 = blockIdx.y * 128 + wc * 64;
    const int r15 = lane & 15, q = lane >> 4;

    size_t aoff[4], boff[4];
#pragma unroll
    for (int s = 0; s < 4; ++s) {
        aoff[s] = (size_t)(tok0 + s * 16 + r15) * D + q * 8;
        boff[s] = (size_t)(col0 + s * 16 + r15) * D + q * 8;
    }

    floatx4 acc[4][4];
#pragma unroll
    for (int i = 0; i < 4; ++i)
#pragma unroll
        for (int j = 0; j < 4; ++j) acc[i][j] = (floatx4){0.f, 0.f, 0.f, 0.f};

    short8 Ah[2][4], Al[2][4], Bh[2][4], Bl[2][4];
#pragma unroll
    for (int s = 0; s < 4; ++s) {
        Ah[0][s] = *(const short8*)(xh + aoff[s]);
        Al[0][s] = *(const short8*)(xl + aoff[s]);
        Bh[0][s] = *(const short8*)(vht + boff[s]);
        Bl[0][s] = *(const short8*)(vlt + boff[s]);
    }

#pragma unroll
    for (int kc = 0; kc < 16; ++kc) {
        const int cur = kc & 1, nxt = cur ^ 1;
        if (kc < 15) {
            const int d0 = (kc + 1) * 32;
#pragma unroll
            for (int s = 0; s < 4; ++s) {
                Ah[nxt][s] = *(const short8*)(xh + aoff[s] + d0);
                Al[nxt][s] = *(const short8*)(xl + aoff[s] + d0);
                Bh[nxt][s] = *(const short8*)(vht + boff[s] + d0);
                Bl[nxt][s] = *(const short8*)(vlt + boff[s] + d0);
            }
        }
#pragma unroll
        for (int st = 0; st < 4; ++st)
#pragma unroll
            for (int sc = 0; sc < 4; ++sc) {
                acc[st][sc] = __builtin_amdgcn_mfma_f32_16x16x32_bf16(Ah[cur][st], Bh[cur][sc], acc[st][sc], 0, 0, 0);
                acc[st][sc] = __builtin_amdgcn_mfma_f32_16x16x32_bf16(Ah[cur][st], Bl[cur][sc], acc[st][sc], 0, 0, 0);
                acc[st][sc] = __builtin_amdgcn_mfma_f32_16x16x32_bf16(Al[cur][st], Bh[cur][sc], acc[st][sc], 0, 0, 0);
            }
    }

#pragma unroll
    for (int sc = 0; sc < 4; ++sc) {
        const int colg = col0 + sc * 16 + r15;
        const float vs = ws[WS_VSCALE + colg];
        const int ex = (col0 >> 4) + sc;
#pragma unroll
        for (int st = 0; st < 4; ++st) {
            const int rowb = tok0 + st * 16 + q * 4;
            float r0 = acc[st][sc][0] * vs;
            float r1 = acc[st][sc][1] * vs;
            float r2 = acc[st][sc][2] * vs;
            float r3 = acc[st][sc][3] * vs;
            rbf[(size_t)(rowb + 0) * NC + colg] = f2bf(r0);
            rbf[(size_t)(rowb + 1) * NC + colg] = f2bf(r1);
            rbf[(size_t)(rowb + 2) * NC + colg] = f2bf(r2);
            rbf[(size_t)(rowb + 3) * NC + colg] = f2bf(r3);
            float e0 = r0 * r0, e1 = r1 * r1, e2 = r2 * r2, e3 = r3 * r3;
#pragma unroll
            for (int mk = 1; mk < 16; mk <<= 1) {
                e0 += __shfl_xor(e0, mk);
                e1 += __shfl_xor(e1, mk);
                e2 += __shfl_xor(e2, mk);
                e3 += __shfl_xor(e3, mk);
            }
            if (r15 == 0) {
                float* ep = ws + WS_E_F + (size_t)rowb * M + ex;
                ep[0] = e0; ep[M] = e1; ep[2 * M] = e2; ep[3 * M] = e3;
            }
        }
    }
}

// MFMA split-bf16 Gram: sum |diag(s) A^T A diag(s) - I| over 64x64 tiles, bi<=bj.
__launch_bounds__(256)
__global__ void mfma_gram(const ushort* __restrict__ aht, const ushort* __restrict__ alt,
                          const float* __restrict__ scales, float* __restrict__ sum_out) {
    const int bi = blockIdx.x, bj = blockIdx.y;
    if (bi > bj) return;
    const int tid = threadIdx.x, lane = tid & 63, w = tid >> 6;
    const int wr = w >> 1, wc = w & 1;
    const int row0 = bi * 64 + wr * 32;
    const int colb0 = bj * 64 + wc * 32;
    const int r15 = lane & 15, q = lane >> 4;

    size_t aoff[2], boff[2];
#pragma unroll
    for (int s = 0; s < 2; ++s) {
        aoff[s] = (size_t)(row0 + s * 16 + r15) * D + q * 8;
        boff[s] = (size_t)(colb0 + s * 16 + r15) * D + q * 8;
    }

    floatx4 acc[2][2];
#pragma unroll
    for (int i = 0; i < 2; ++i)
#pragma unroll
        for (int j = 0; j < 2; ++j) acc[i][j] = (floatx4){0.f, 0.f, 0.f, 0.f};

    short8 Ah[2][2], Al[2][2], Bh[2][2], Bl[2][2];
#pragma unroll
    for (int s = 0; s < 2; ++s) {
        Ah[0][s] = *(const short8*)(aht + aoff[s]);
        Al[0][s] = *(const short8*)(alt + aoff[s]);
        Bh[0][s] = *(const short8*)(aht + boff[s]);
        Bl[0][s] = *(const short8*)(alt + boff[s]);
    }
#pragma unroll
    for (int kc = 0; kc < 16; ++kc) {
        const int cur = kc & 1, nxt = cur ^ 1;
        if (kc < 15) {
            const int d0 = (kc + 1) * 32;
#pragma unroll
            for (int s = 0; s < 2; ++s) {
                Ah[nxt][s] = *(const short8*)(aht + aoff[s] + d0);
                Al[nxt][s] = *(const short8*)(alt + aoff[s] + d0);
                Bh[nxt][s] = *(const short8*)(aht + boff[s] + d0);
                Bl[nxt][s] = *(const short8*)(alt + boff[s] + d0);
            }
        }
#pragma unroll
        for (int si = 0; si < 2; ++si)
#pragma unroll
            for (int sj = 0; sj < 2; ++sj) {
                acc[si][sj] = __builtin_amdgcn_mfma_f32_16x16x32_bf16(Ah[cur][si], Bh[cur][sj], acc[si][sj], 0, 0, 0);
                acc[si][sj] = __builtin_amdgcn_mfma_f32_16x16x32_bf16(Ah[cur][si], Bl[cur][sj], acc[si][sj], 0, 0, 0);
                acc[si][sj] = __builtin_amdgcn_mfma_f32_16x16x32_bf16(Al[cur][si], Bh[cur][sj], acc[si][sj], 0, 0, 0);
            }
    }

    float local = 0.0f;
#pragma unroll
    for (int si = 0; si < 2; ++si)
#pragma unroll
        for (int sj = 0; sj < 2; ++sj) {
            const int colg = colb0 + sj * 16 + r15;
            const float scj = scales[colg];
#pragma unroll
            for (int reg = 0; reg < 4; ++reg) {
                const int rowg = row0 + si * 16 + q * 4 + reg;
                float g = acc[si][sj][reg] * scales[rowg] * scj;
                if (rowg == colg) g -= 1.0f;
                local += fabsf(g);
            }
        }
    if (bi < bj) local *= 2.0f;

#pragma unroll
    for (int mk = 1; mk < 64; mk <<= 1) local += __shfl_xor(local, mk);
    __shared__ float red[4];
    if (lane == 0) red[w] = local;
    __syncthreads();
    if (tid == 0) atomicAdd(sum_out, (red[0] + red[1]) + (red[2] + red[3]));
}

// top-4 (exact jax semantics) + aux atomics + per-expert lists + out = x init
__launch_bounds__(256)
__global__ void topk_kernel(const float* __restrict__ x,
                            float* __restrict__ ws,
                            float* __restrict__ out) {
    __shared__ float en[TTB][M];
    __shared__ int   sidx[TTB][KSEL];

    const int tid = threadIdx.x;
    const int t0 = blockIdx.x * TTB;

#pragma unroll
    for (int i = 0; i < (TTB * M) / 256; ++i)
        ((float*)en)[i * 256 + tid] = ws[WS_E_F + (size_t)t0 * M + i * 256 + tid];
    __syncthreads();

    if (tid < TTB) {
        float bv0 = -1e30f, bv1 = -1e30f, bv2 = -1e30f, bv3 = -1e30f;
        int bi0 = 0, bi1 = 0, bi2 = 0, bi3 = 0;
        for (int m = 0; m < M; ++m) {
            float v = en[tid][m];
            if (v > bv3) {
                if (v > bv0) {
                    bv3 = bv2; bi3 = bi2; bv2 = bv1; bi2 = bi1; bv1 = bv0; bi1 = bi0;
                    bv0 = v; bi0 = m;
                } else if (v > bv1) {
                    bv3 = bv2; bi3 = bi2; bv2 = bv1; bi2 = bi1;
                    bv1 = v; bi1 = m;
                } else if (v > bv2) {
                    bv3 = bv2; bi3 = bi2;
                    bv2 = v; bi2 = m;
                } else {
                    bv3 = v; bi3 = m;
                }
            }
        }
        sidx[tid][0] = bi0; sidx[tid][1] = bi1; sidx[tid][2] = bi2; sidx[tid][3] = bi3;
        atomicAdd(&ws[WS_EACC + bi0], bv0); atomicAdd(&ws[WS_CACC + bi0], 1.0f);
        atomicAdd(&ws[WS_EACC + bi1], bv1); atomicAdd(&ws[WS_CACC + bi1], 1.0f);
        atomicAdd(&ws[WS_EACC + bi2], bv2); atomicAdd(&ws[WS_CACC + bi2], 1.0f);
        atomicAdd(&ws[WS_EACC + bi3], bv3); atomicAdd(&ws[WS_CACC + bi3], 1.0f);
    }
    __syncthreads();

    // append (token) to each selected expert's list
    if (tid < TTB * KSEL) {
        const int t = tid >> 2, k = tid & 3;
        const int e = sidx[t][k];
        int* icnt = (int*)ws + WS_CNT_I;
        int* ilist = (int*)(ws + WS_LIST_F);
        int pos = atomicAdd(&icnt[e], 1);
        ilist[(e << 12) + pos] = t0 + t;
    }

    // out = x for this block's 4 tokens (residual base; scatter adds later)
#pragma unroll
    for (int i = 0; i < 2; ++i) {
        const int idx = i * 1024 + tid * 4;
        const int t = idx >> 9, d = idx & 511;
        *(float4*)(out + (size_t)(t0 + t) * D + d) =
            *(const float4*)(x + (size_t)(t0 + t) * D + d);
    }
}

// Expert-major scatter: block (e, chunk). U[e] slice lives in registers
// (uscale folded in); per token: broadcast 16 bf16 r-values, 32 FMA,
// 2 coalesced atomicAdds into out.
__launch_bounds__(256)
__global__ void expert_scatter_kernel(const float* __restrict__ U,
                                      const ushort* __restrict__ rbf,
                                      const float* __restrict__ ws,
                                      float* __restrict__ out) {
    const int e = blockIdx.x;
    const int tid = threadIdx.x;
    const int cnt = ((const int*)ws)[WS_CNT_I + e];
    if ((int)blockIdx.y >= cnt) return;

    // U[e][d][b] for d = tid and tid+256, b=0..15; fold uscale[e*16+b]
    float usc[16];
#pragma unroll
    for (int b = 0; b < 16; ++b) usc[b] = ws[WS_USCALE + (e << 4) + b];

    const float* Up = U + (size_t)e * (D * B);
    float u0[16], u1[16];
#pragma unroll
    for (int qd = 0; qd < 4; ++qd) {
        float4 a = *(const float4*)(Up + (size_t)tid * B + qd * 4);
        float4 b4 = *(const float4*)(Up + (size_t)(tid + 256) * B + qd * 4);
        u0[qd * 4 + 0] = a.x * usc[qd * 4 + 0];
        u0[qd * 4 + 1] = a.y * usc[qd * 4 + 1];
        u0[qd * 4 + 2] = a.z * usc[qd * 4 + 2];
        u0[qd * 4 + 3] = a.w * usc[qd * 4 + 3];
        u1[qd * 4 + 0] = b4.x * usc[qd * 4 + 0];
        u1[qd * 4 + 1] = b4.y * usc[qd * 4 + 1];
        u1[qd * 4 + 2] = b4.z * usc[qd * 4 + 2];
        u1[qd * 4 + 3] = b4.w * usc[qd * 4 + 3];
    }

    const int* ilist = (const int*)(ws + WS_LIST_F) + (e << 12);
    for (int i = blockIdx.y; i < cnt; i += 16) {
        const int t = ilist[i];
        const ushort* rp = rbf + (size_t)t * NC + (e << 4);
        union { ushort u[16]; uint4 q[2]; } R;
        R.q[0] = *(const uint4*)(rp);
        R.q[1] = *(const uint4*)(rp + 8);
        float acc0 = 0.0f, acc1 = 0.0f;
#pragma unroll
        for (int b = 0; b < 16; ++b) {
            const float wv = bf2f(R.u[b]);
            acc0 = fmaf(u0[b], wv, acc0);
            acc1 = fmaf(u1[b], wv, acc1);
        }
        atomicAdd(out + (size_t)t * D + tid, acc0);
        atomicAdd(out + (size_t)t * D + 256 + tid, acc1);
    }
}

__global__ void finalize_kernel(const float* __restrict__ ws, float* __restrict__ out) {
    const int m = threadIdx.x;   // 128 threads
    float e = ws[WS_EACC + m] * (1.0f / (float)NTOK);
    float c = ws[WS_CACC + m] * (1.0f / (float)NTOK);

    float s = e;
#pragma unroll
    for (int off = 32; off > 0; off >>= 1) s += __shfl_down(s, off);
    __shared__ float sh[2];
    if ((m & 63) == 0) sh[m >> 6] = s;
    __syncthreads();
    float total = sh[0] + sh[1];
    float total_energy = fmaxf(total, 1e-12f);

    out[OUT_EPE + m] = e;
    out[OUT_RE + m] = e / total_energy;
    out[OUT_SR + m] = c;
    if (m == 0) {
        out[OUT_TE] = total_energy;
        float inv_n2 = 1.0f / ((float)NC * (float)NC);
        float sqrtD = sqrtf((float)D);
        float vpen = ws[WS_VSUM] * inv_n2 * sqrtD;
        float upen = ws[WS_USUM] * inv_n2 * sqrtD;
        out[OUT_VPEN] = vpen;
        out[OUT_UPEN] = upen;
        out[OUT_AUX] = 0.01f * vpen - total_energy;
    }
}

extern "C" void kernel_launch(void* const* d_in, const int* in_sizes, int n_in,
                              void* d_out, int out_size, void* d_ws, size_t ws_size,
                              hipStream_t stream) {
    const float* x  = (const float*)d_in[0];
    const float* V  = (const float*)d_in[1];
    const float* U  = (const float*)d_in[2];
    const float* us = (const float*)d_in[3];
    float* out = (float*)d_out;
    float* ws  = (float*)d_ws;

    ushort* xh  = (ushort*)(ws + WS_XH_F);
    ushort* xl  = (ushort*)(ws + WS_XL_F);
    ushort* vht = (ushort*)(ws + WS_VHT_F);
    ushort* vlt = (ushort*)(ws + WS_VLT_F);
    ushort* uht = (ushort*)(ws + WS_UHT_F);
    ushort* ult = (ushort*)(ws + WS_ULT_F);
    ushort* rbf = (ushort*)(ws + WS_RBF_F);

    init_ws_kernel<<<2, 256, 0, stream>>>(ws);
    convert_x<<<1024, 256, 0, stream>>>(x, xh, xl);
    convert_VT<<<dim3(32, 8), 256, 0, stream>>>(V, vht, vlt);
    convert_UT<<<128, 256, 0, stream>>>(U, uht, ult);
    scales_kernel<<<160, 256, 0, stream>>>(V, U, us, ws);
    mfma_gemm<<<dim3(32, 16), 256, 0, stream>>>(xh, xl, vht, vlt, ws, rbf);
    topk_kernel<<<NTOK / TTB, 256, 0, stream>>>(x, ws, out);
    expert_scatter_kernel<<<dim3(128, 16), 256, 0, stream>>>(U, rbf, ws, out);
    mfma_gram<<<dim3(32, 32), 256, 0, stream>>>(vht, vlt, ws + WS_VSCALE, ws + WS_VSUM);
    mfma_gram<<<dim3(32, 32), 256, 0, stream>>>(uht, ult, ws + WS_USCALE, ws + WS_USUM);
    finalize_kernel<<<1, 128, 0, stream>>>(ws, out);
}

// Round 6
// 236.882 us; speedup vs baseline: 2.3244x; 1.5691x over previous
//
#include <hip/hip_runtime.h>
#include <math.h>

#define D 512
#define M 128
#define B 16
#define KSEL 4
#define NC 2048           // M*B
#define NTOK 4096         // 2*2048
#define TTB 4             // tokens per block in topk kernel

typedef unsigned short ushort;
typedef unsigned int uint;
typedef __attribute__((ext_vector_type(8))) short short8;   // 8 bf16 (4 VGPRs)
typedef __attribute__((ext_vector_type(4))) float floatx4;  // 4 fp32 acc

// ws layout (float indices)
#define WS_EACC   0       // [128]
#define WS_CACC   128     // [128]
#define WS_VSUM   256     // [1]
#define WS_USUM   257     // [1]
#define WS_CNT_I  258     // int counters [128] (inside zeroed first 512 floats)
#define WS_VSCALE 512     // [2048] 1/||V col||
#define WS_USCALE 2560    // [2048] tanh(us)/||U col||
#define WS_E_F    4608    // [NTOK*M] fp32 energies, 2 MB
#define WS_RBF_F  528896  // R bf16 [NTOK][NC] (16 MB)
#define WS_XH_F   2626048 // xh bf16 [NTOK][D]; REUSED as contrib after gram
#define WS_XL_F   3674624 // xl bf16
#define WS_VHT_F  4723200 // VhT bf16 [NC][D]
#define WS_VLT_F  5247488
#define WS_UHT_F  5771776 // UhT bf16 [NC][D] (col = m*16+b)
#define WS_ULT_F  6296064
#define WS_LIST_F 6820352 // int [128][4096] per-expert token lists, packed (t<<2)|k
                          // end: 7344640 floats = 29.4 MB
// contrib (packed bf16 pairs, as uint): 4,194,304 uints at WS_XH_F..WS_LIST_F (16 MB)

// out layout (floats)
#define OUT_TE   2097152
#define OUT_EPE  2097153
#define OUT_RE   2097281
#define OUT_SR   2097409
#define OUT_VPEN 2097537
#define OUT_UPEN 2097538
#define OUT_AUX  2097539

#define GLDS16(g, l) __builtin_amdgcn_global_load_lds(                        \
    (const __attribute__((address_space(1))) unsigned int*)(g),               \
    (__attribute__((address_space(3))) unsigned int*)(l), 16, 0, 0)

__device__ __forceinline__ ushort f2bf(float f) {   // RNE
    union { float f; uint u; } a; a.f = f;
    uint u = a.u;
    u += 0x7fffu + ((u >> 16) & 1u);
    return (ushort)(u >> 16);
}
__device__ __forceinline__ float bf2f(ushort h) {
    union { uint u; float f; } a; a.u = ((uint)h) << 16;
    return a.f;
}

__global__ void init_ws_kernel(float* __restrict__ ws) {
    int i = blockIdx.x * 256 + threadIdx.x;
    if (i < 512) ws[i] = 0.0f;
}

__global__ void convert_x(const float* __restrict__ x, ushort* __restrict__ xh,
                          ushort* __restrict__ xl) {
    const int idx = (blockIdx.x * 256 + threadIdx.x) * 8;
    float4 v0 = *(const float4*)(x + idx);
    float4 v1 = *(const float4*)(x + idx + 4);
    float vv[8] = {v0.x, v0.y, v0.z, v0.w, v1.x, v1.y, v1.z, v1.w};
    union { ushort u[8]; uint4 q; } H, L;
#pragma unroll
    for (int j = 0; j < 8; ++j) {
        ushort h = f2bf(vv[j]);
        H.u[j] = h;
        L.u[j] = f2bf(vv[j] - bf2f(h));
    }
    *(uint4*)(xh + idx) = H.q;
    *(uint4*)(xl + idx) = L.q;
}

__global__ void convert_VT(const float* __restrict__ V, ushort* __restrict__ vht,
                           ushort* __restrict__ vlt) {
    __shared__ float ts[64][65];
    const int tid = threadIdx.x;
    const int col0 = blockIdx.x * 64;
    const int d0 = blockIdx.y * 64;
#pragma unroll
    for (int i = 0; i < 16; ++i) {
        int idx = i * 256 + tid;
        int r = idx >> 6, c = idx & 63;
        ts[r][c] = V[(size_t)(d0 + r) * NC + col0 + c];
    }
    __syncthreads();
#pragma unroll
    for (int i = 0; i < 16; ++i) {
        int idx = i * 256 + tid;
        int c2 = idx >> 6, d2 = idx & 63;
        float v = ts[d2][c2];
        ushort h = f2bf(v);
        vht[(size_t)(col0 + c2) * D + d0 + d2] = h;
        vlt[(size_t)(col0 + c2) * D + d0 + d2] = f2bf(v - bf2f(h));
    }
}

__global__ void convert_UT(const float* __restrict__ U, ushort* __restrict__ uht,
                           ushort* __restrict__ ult) {
    __shared__ float ts[16][129];
    const int tid = threadIdx.x;
    const int m = blockIdx.x;
    for (int d0 = 0; d0 < D; d0 += 128) {
        __syncthreads();
#pragma unroll
        for (int i = 0; i < 8; ++i) {
            int idx = i * 256 + tid;
            int d2 = idx >> 4, b2 = idx & 15;
            ts[b2][d2] = U[(size_t)m * (D * B) + (size_t)(d0 + d2) * B + b2];
        }
        __syncthreads();
#pragma unroll
        for (int i = 0; i < 8; ++i) {
            int idx = i * 256 + tid;
            int b3 = idx >> 7, d3 = idx & 127;
            float v = ts[b3][d3];
            ushort h = f2bf(v);
            uht[(size_t)((m << 4) + b3) * D + d0 + d3] = h;
            ult[(size_t)((m << 4) + b3) * D + d0 + d3] = f2bf(v - bf2f(h));
        }
    }
}

__global__ void scales_kernel(const float* __restrict__ V,
                              const float* __restrict__ U,
                              const float* __restrict__ us_in,
                              float* __restrict__ ws) {
    const int bx = blockIdx.x;
    const int tid = threadIdx.x;
    if (bx < 32) {
        const int c = bx * 64 + (tid & 63);
        const int dg = tid >> 6;
        float s = 0.0f;
        for (int d = dg; d < D; d += 4) {
            float v = V[(size_t)d * NC + c];
            s = fmaf(v, v, s);
        }
        __shared__ float sh[4][64];
        sh[dg][tid & 63] = s;
        __syncthreads();
        if (tid < 64) {
            float t = (sh[0][tid] + sh[1][tid]) + (sh[2][tid] + sh[3][tid]);
            ws[WS_VSCALE + bx * 64 + tid] = 1.0f / sqrtf(t);
        }
    } else {
        const int m = bx - 32;
        const float* p = U + (size_t)m * (D * B);
        float s = 0.0f;
        for (int i = tid; i < D * B; i += 256) {
            float v = p[i];
            s = fmaf(v, v, s);
        }
        __shared__ float sh2[256];
        sh2[tid] = s;
        __syncthreads();
        if (tid < 16) {
            float t = 0.0f;
#pragma unroll
            for (int j = 0; j < 16; ++j) t += sh2[tid + (j << 4)];
            ws[WS_USCALE + (m << 4) + tid] = tanhf(us_in[(m << 4) + tid]) / sqrtf(t);
        }
    }
}

// LDS-staged split-bf16 MFMA GEMM: R = (x @ V)*vscale (bf16) + E energies.
// 128x128 tile, BK=32, double-buffered 64KB LDS, global_load_lds width 16,
// XOR k-slot swizzle so ds_read_b128 is 2-way (free) instead of 8-way.
__launch_bounds__(256)
__global__ void mfma_gemm(const ushort* __restrict__ xh, const ushort* __restrict__ xl,
                          const ushort* __restrict__ vht, const ushort* __restrict__ vlt,
                          float* __restrict__ ws, ushort* __restrict__ rbf) {
    __shared__ ushort smem[32768];   // 2 bufs x 4 tiles x (128 rows x 32 bf16)
    const int tid = threadIdx.x, lane = tid & 63, w = tid >> 6;
    const int wr = w >> 1, wc = w & 1;
    const int tokB = blockIdx.x * 128, colB = blockIdx.y * 128;
    const int r15 = lane & 15, q = lane >> 4;

    // staging coords (per lane)
    const int srl = lane >> 2;                         // row-in-16
    const int skq = (lane & 3) ^ ((lane >> 3) & 3);    // swizzled k-slot
    // compute-side swizzled k offset (ushorts)
    const int perm8 = (q ^ ((r15 >> 1) & 3)) * 8;

    floatx4 acc[4][4];
#pragma unroll
    for (int i = 0; i < 4; ++i)
#pragma unroll
        for (int j = 0; j < 4; ++j) acc[i][j] = (floatx4){0.f, 0.f, 0.f, 0.f};

    const ushort* srcs[4] = {xh, xl, vht, vlt};
    const int rbase[4] = {tokB, tokB, colB, colB};

    auto stage = [&](int buf, int c) {
        const int kb = c * 32 + skq * 8;
#pragma unroll
        for (int tI = 0; tI < 4; ++tI) {
            const ushort* s = srcs[tI] + (size_t)rbase[tI] * D + kb;
#pragma unroll
            for (int sub = 0; sub < 2; ++sub) {
                const int row16 = w * 32 + sub * 16;
                GLDS16(s + (size_t)(row16 + srl) * D,
                       &smem[buf * 16384 + tI * 4096 + row16 * 32]);
            }
        }
    };

    stage(0, 0);
    for (int c = 0; c < 16; ++c) {
        __syncthreads();
        if (c < 15) stage((c + 1) & 1, c + 1);
        const ushort* bp = &smem[(c & 1) * 16384];
        short8 ah[4], al[4], bh[4], bl[4];
#pragma unroll
        for (int s = 0; s < 4; ++s) {
            const int ra = (wr * 64 + s * 16 + r15) * 32 + perm8;
            ah[s] = *(const short8*)&bp[ra];
            al[s] = *(const short8*)&bp[4096 + ra];
            const int rb = (wc * 64 + s * 16 + r15) * 32 + perm8;
            bh[s] = *(const short8*)&bp[8192 + rb];
            bl[s] = *(const short8*)&bp[12288 + rb];
        }
#pragma unroll
        for (int st = 0; st < 4; ++st)
#pragma unroll
            for (int sc = 0; sc < 4; ++sc) {
                acc[st][sc] = __builtin_amdgcn_mfma_f32_16x16x32_bf16(ah[st], bh[sc], acc[st][sc], 0, 0, 0);
                acc[st][sc] = __builtin_amdgcn_mfma_f32_16x16x32_bf16(ah[st], bl[sc], acc[st][sc], 0, 0, 0);
                acc[st][sc] = __builtin_amdgcn_mfma_f32_16x16x32_bf16(al[st], bh[sc], acc[st][sc], 0, 0, 0);
            }
    }

    // Epilogue: fold vscale; store bf16 R; energy shuffle-reduce per (tok, expert).
    const int tok0 = tokB + wr * 64, col0 = colB + wc * 64;
#pragma unroll
    for (int sc = 0; sc < 4; ++sc) {
        const int colg = col0 + sc * 16 + r15;
        const float vs = ws[WS_VSCALE + colg];
        const int ex = colg >> 4;
#pragma unroll
        for (int st = 0; st < 4; ++st) {
            const int rowb = tok0 + st * 16 + q * 4;
            float r0 = acc[st][sc][0] * vs;
            float r1 = acc[st][sc][1] * vs;
            float r2 = acc[st][sc][2] * vs;
            float r3 = acc[st][sc][3] * vs;
            rbf[(size_t)(rowb + 0) * NC + colg] = f2bf(r0);
            rbf[(size_t)(rowb + 1) * NC + colg] = f2bf(r1);
            rbf[(size_t)(rowb + 2) * NC + colg] = f2bf(r2);
            rbf[(size_t)(rowb + 3) * NC + colg] = f2bf(r3);
            float e0 = r0 * r0, e1 = r1 * r1, e2 = r2 * r2, e3 = r3 * r3;
#pragma unroll
            for (int mk = 1; mk < 16; mk <<= 1) {
                e0 += __shfl_xor(e0, mk);
                e1 += __shfl_xor(e1, mk);
                e2 += __shfl_xor(e2, mk);
                e3 += __shfl_xor(e3, mk);
            }
            if (r15 == 0) {
                float* ep = ws + WS_E_F + (size_t)rowb * M + ex;
                ep[0] = e0; ep[M] = e1; ep[2 * M] = e2; ep[3 * M] = e3;
            }
        }
    }
}

// Merged V+U Gram: 272 blocks; 128x128 tiles over the upper triangle (x2 off-diag).
__launch_bounds__(256)
__global__ void mfma_gram2(const ushort* __restrict__ vht, const ushort* __restrict__ vlt,
                           const ushort* __restrict__ uht, const ushort* __restrict__ ult,
                           float* __restrict__ ws) {
    __shared__ ushort smem[32768];
    int bid = blockIdx.x;
    const int which = bid >= 136;
    int t = which ? bid - 136 : bid;
    int bi = 0, rem = 16;
    while (t >= rem) { t -= rem; --rem; ++bi; }
    const int bj = bi + t;

    const ushort* ht = which ? uht : vht;
    const ushort* lt = which ? ult : vlt;
    const float* scl = ws + (which ? WS_USCALE : WS_VSCALE);
    float* sum_out = ws + (which ? WS_USUM : WS_VSUM);

    const int tid = threadIdx.x, lane = tid & 63, w = tid >> 6;
    const int wr = w >> 1, wc = w & 1;
    const int r15 = lane & 15, q = lane >> 4;
    const int srl = lane >> 2;
    const int skq = (lane & 3) ^ ((lane >> 3) & 3);
    const int perm8 = (q ^ ((r15 >> 1) & 3)) * 8;

    floatx4 acc[4][4];
#pragma unroll
    for (int i = 0; i < 4; ++i)
#pragma unroll
        for (int j = 0; j < 4; ++j) acc[i][j] = (floatx4){0.f, 0.f, 0.f, 0.f};

    const ushort* srcs[4] = {ht, lt, ht, lt};
    const int rbase[4] = {bi * 128, bi * 128, bj * 128, bj * 128};

    auto stage = [&](int buf, int c) {
        const int kb = c * 32 + skq * 8;
#pragma unroll
        for (int tI = 0; tI < 4; ++tI) {
            const ushort* s = srcs[tI] + (size_t)rbase[tI] * D + kb;
#pragma unroll
            for (int sub = 0; sub < 2; ++sub) {
                const int row16 = w * 32 + sub * 16;
                GLDS16(s + (size_t)(row16 + srl) * D,
                       &smem[buf * 16384 + tI * 4096 + row16 * 32]);
            }
        }
    };

    stage(0, 0);
    for (int c = 0; c < 16; ++c) {
        __syncthreads();
        if (c < 15) stage((c + 1) & 1, c + 1);
        const ushort* bp = &smem[(c & 1) * 16384];
        short8 ah[4], al[4], bh[4], bl[4];
#pragma unroll
        for (int s = 0; s < 4; ++s) {
            const int ra = (wr * 64 + s * 16 + r15) * 32 + perm8;
            ah[s] = *(const short8*)&bp[ra];
            al[s] = *(const short8*)&bp[4096 + ra];
            const int rb = (wc * 64 + s * 16 + r15) * 32 + perm8;
            bh[s] = *(const short8*)&bp[8192 + rb];
            bl[s] = *(const short8*)&bp[12288 + rb];
        }
#pragma unroll
        for (int st = 0; st < 4; ++st)
#pragma unroll
            for (int sc = 0; sc < 4; ++sc) {
                acc[st][sc] = __builtin_amdgcn_mfma_f32_16x16x32_bf16(ah[st], bh[sc], acc[st][sc], 0, 0, 0);
                acc[st][sc] = __builtin_amdgcn_mfma_f32_16x16x32_bf16(ah[st], bl[sc], acc[st][sc], 0, 0, 0);
                acc[st][sc] = __builtin_amdgcn_mfma_f32_16x16x32_bf16(al[st], bh[sc], acc[st][sc], 0, 0, 0);
            }
    }

    float local = 0.0f;
#pragma unroll
    for (int sc = 0; sc < 4; ++sc) {
        const int colg = bj * 128 + wc * 64 + sc * 16 + r15;
        const float scj = scl[colg];
#pragma unroll
        for (int st = 0; st < 4; ++st) {
#pragma unroll
            for (int reg = 0; reg < 4; ++reg) {
                const int rowg = bi * 128 + wr * 64 + st * 16 + q * 4 + reg;
                float g = acc[st][sc][reg] * scl[rowg] * scj;
                if (rowg == colg) g -= 1.0f;
                local += fabsf(g);
            }
        }
    }
    if (bi < bj) local *= 2.0f;

#pragma unroll
    for (int mk = 1; mk < 64; mk <<= 1) local += __shfl_xor(local, mk);
    __shared__ float red[4];
    if (lane == 0) red[w] = local;
    __syncthreads();
    if (tid == 0) atomicAdd(sum_out, (red[0] + red[1]) + (red[2] + red[3]));
}

// top-4 (exact jax semantics) + aux atomics + per-expert packed lists
__launch_bounds__(256)
__global__ void topk_kernel(float* __restrict__ ws) {
    __shared__ float en[TTB][M];
    __shared__ int   sidx[TTB][KSEL];

    const int tid = threadIdx.x;
    const int t0 = blockIdx.x * TTB;

#pragma unroll
    for (int i = 0; i < (TTB * M) / 256; ++i)
        ((float*)en)[i * 256 + tid] = ws[WS_E_F + (size_t)t0 * M + i * 256 + tid];
    __syncthreads();

    if (tid < TTB) {
        float bv0 = -1e30f, bv1 = -1e30f, bv2 = -1e30f, bv3 = -1e30f;
        int bi0 = 0, bi1 = 0, bi2 = 0, bi3 = 0;
        for (int m = 0; m < M; ++m) {
            float v = en[tid][m];
            if (v > bv3) {
                if (v > bv0) {
                    bv3 = bv2; bi3 = bi2; bv2 = bv1; bi2 = bi1; bv1 = bv0; bi1 = bi0;
                    bv0 = v; bi0 = m;
                } else if (v > bv1) {
                    bv3 = bv2; bi3 = bi2; bv2 = bv1; bi2 = bi1;
                    bv1 = v; bi1 = m;
                } else if (v > bv2) {
                    bv3 = bv2; bi3 = bi2;
                    bv2 = v; bi2 = m;
                } else {
                    bv3 = v; bi3 = m;
                }
            }
        }
        sidx[tid][0] = bi0; sidx[tid][1] = bi1; sidx[tid][2] = bi2; sidx[tid][3] = bi3;
        atomicAdd(&ws[WS_EACC + bi0], bv0); atomicAdd(&ws[WS_CACC + bi0], 1.0f);
        atomicAdd(&ws[WS_EACC + bi1], bv1); atomicAdd(&ws[WS_CACC + bi1], 1.0f);
        atomicAdd(&ws[WS_EACC + bi2], bv2); atomicAdd(&ws[WS_CACC + bi2], 1.0f);
        atomicAdd(&ws[WS_EACC + bi3], bv3); atomicAdd(&ws[WS_CACC + bi3], 1.0f);
    }
    __syncthreads();

    if (tid < TTB * KSEL) {
        const int t = tid >> 2, k = tid & 3;
        const int e = sidx[t][k];
        int* icnt = (int*)ws + WS_CNT_I;
        int* ilist = (int*)(ws + WS_LIST_F);
        int pos = atomicAdd(&icnt[e], 1);
        ilist[(e << 12) + pos] = ((t0 + t) << 2) | k;
    }
}

// Expert-major contributions: contrib[t][k][d] (bf16 pairs packed in uint).
// Plain coalesced stores — no atomics.
__launch_bounds__(256)
__global__ void expert_contrib_kernel(const float* __restrict__ U,
                                      const ushort* __restrict__ rbf,
                                      const float* __restrict__ ws,
                                      uint* __restrict__ contrib) {
    const int e = blockIdx.x;
    const int tid = threadIdx.x;
    const int cnt = ((const int*)ws)[WS_CNT_I + e];
    if ((int)blockIdx.y * 1 >= cnt && blockIdx.y >= (uint)cnt) return;

    float usc[16];
#pragma unroll
    for (int b = 0; b < 16; ++b) usc[b] = ws[WS_USCALE + (e << 4) + b];

    // thread covers d = 2*tid, 2*tid+1
    const float* Up = U + (size_t)e * (D * B);
    float u0[16], u1[16];
#pragma unroll
    for (int qd = 0; qd < 4; ++qd) {
        float4 a = *(const float4*)(Up + (size_t)(2 * tid) * B + qd * 4);
        float4 b4 = *(const float4*)(Up + (size_t)(2 * tid + 1) * B + qd * 4);
        u0[qd * 4 + 0] = a.x * usc[qd * 4 + 0];
        u0[qd * 4 + 1] = a.y * usc[qd * 4 + 1];
        u0[qd * 4 + 2] = a.z * usc[qd * 4 + 2];
        u0[qd * 4 + 3] = a.w * usc[qd * 4 + 3];
        u1[qd * 4 + 0] = b4.x * usc[qd * 4 + 0];
        u1[qd * 4 + 1] = b4.y * usc[qd * 4 + 1];
        u1[qd * 4 + 2] = b4.z * usc[qd * 4 + 2];
        u1[qd * 4 + 3] = b4.w * usc[qd * 4 + 3];
    }

    const int* ilist = (const int*)(ws + WS_LIST_F) + (e << 12);
    int i = blockIdx.y;
    int pk = (i < cnt) ? ilist[i] : 0;
    while (i < cnt) {
        const int t = pk >> 2, k = pk & 3;
        const ushort* rp = rbf + (size_t)t * NC + (e << 4);
        union { ushort u[16]; uint4 q[2]; } R;
        R.q[0] = *(const uint4*)(rp);
        R.q[1] = *(const uint4*)(rp + 8);
        const int inext = i + 4;
        if (inext < cnt) pk = ilist[inext];
        float acc0 = 0.0f, acc1 = 0.0f;
#pragma unroll
        for (int b = 0; b < 16; ++b) {
            const float wv = bf2f(R.u[b]);
            acc0 = fmaf(u0[b], wv, acc0);
            acc1 = fmaf(u1[b], wv, acc1);
        }
        contrib[(size_t)((t << 2) + k) * 256 + tid] =
            (uint)f2bf(acc0) | ((uint)f2bf(acc1) << 16);
        i = inext;
    }
}

// out[t][d] = x[t][d] + sum_k contrib[t][k][d]  (streaming, coalesced)
__launch_bounds__(256)
__global__ void combine_kernel(const float* __restrict__ x,
                               const uint* __restrict__ contrib,
                               float* __restrict__ out) {
    const int gid = blockIdx.x * 256 + threadIdx.x;   // 0..262143
    const int t = gid >> 6;
    const int dq = (gid & 63) << 3;                   // d base, 8 per thread
    const uint4* cp = (const uint4*)contrib;

    float s[8];
    float4 x0 = *(const float4*)(x + (size_t)t * D + dq);
    float4 x1 = *(const float4*)(x + (size_t)t * D + dq + 4);
    s[0] = x0.x; s[1] = x0.y; s[2] = x0.z; s[3] = x0.w;
    s[4] = x1.x; s[5] = x1.y; s[6] = x1.z; s[7] = x1.w;
#pragma unroll
    for (int k = 0; k < KSEL; ++k) {
        uint4 cvec = cp[(size_t)((t << 2) + k) * 64 + (dq >> 3)];
        uint cc[4] = {cvec.x, cvec.y, cvec.z, cvec.w};
#pragma unroll
        for (int j = 0; j < 4; ++j) {
            s[2 * j]     += bf2f((ushort)(cc[j] & 0xffffu));
            s[2 * j + 1] += bf2f((ushort)(cc[j] >> 16));
        }
    }
    float* op = out + (size_t)t * D + dq;
    *(float4*)(op)     = make_float4(s[0], s[1], s[2], s[3]);
    *(float4*)(op + 4) = make_float4(s[4], s[5], s[6], s[7]);
}

__global__ void finalize_kernel(const float* __restrict__ ws, float* __restrict__ out) {
    const int m = threadIdx.x;   // 128 threads
    float e = ws[WS_EACC + m] * (1.0f / (float)NTOK);
    float c = ws[WS_CACC + m] * (1.0f / (float)NTOK);

    float s = e;
#pragma unroll
    for (int off = 32; off > 0; off >>= 1) s += __shfl_down(s, off);
    __shared__ float sh[2];
    if ((m & 63) == 0) sh[m >> 6] = s;
    __syncthreads();
    float total = sh[0] + sh[1];
    float total_energy = fmaxf(total, 1e-12f);

    out[OUT_EPE + m] = e;
    out[OUT_RE + m] = e / total_energy;
    out[OUT_SR + m] = c;
    if (m == 0) {
        out[OUT_TE] = total_energy;
        float inv_n2 = 1.0f / ((float)NC * (float)NC);
        float sqrtD = sqrtf((float)D);
        float vpen = ws[WS_VSUM] * inv_n2 * sqrtD;
        float upen = ws[WS_USUM] * inv_n2 * sqrtD;
        out[OUT_VPEN] = vpen;
        out[OUT_UPEN] = upen;
        out[OUT_AUX] = 0.01f * vpen - total_energy;
    }
}

extern "C" void kernel_launch(void* const* d_in, const int* in_sizes, int n_in,
                              void* d_out, int out_size, void* d_ws, size_t ws_size,
                              hipStream_t stream) {
    const float* x  = (const float*)d_in[0];
    const float* V  = (const float*)d_in[1];
    const float* U  = (const float*)d_in[2];
    const float* us = (const float*)d_in[3];
    float* out = (float*)d_out;
    float* ws  = (float*)d_ws;

    ushort* xh  = (ushort*)(ws + WS_XH_F);
    ushort* xl  = (ushort*)(ws + WS_XL_F);
    ushort* vht = (ushort*)(ws + WS_VHT_F);
    ushort* vlt = (ushort*)(ws + WS_VLT_F);
    ushort* uht = (ushort*)(ws + WS_UHT_F);
    ushort* ult = (ushort*)(ws + WS_ULT_F);
    ushort* rbf = (ushort*)(ws + WS_RBF_F);
    uint* contrib = (uint*)(ws + WS_XH_F);   // reuses xh..ult after gram

    init_ws_kernel<<<2, 256, 0, stream>>>(ws);
    convert_x<<<1024, 256, 0, stream>>>(x, xh, xl);
    convert_VT<<<dim3(32, 8), 256, 0, stream>>>(V, vht, vlt);
    convert_UT<<<128, 256, 0, stream>>>(U, uht, ult);
    scales_kernel<<<160, 256, 0, stream>>>(V, U, us, ws);
    mfma_gemm<<<dim3(32, 16), 256, 0, stream>>>(xh, xl, vht, vlt, ws, rbf);
    topk_kernel<<<NTOK / TTB, 256, 0, stream>>>(ws);
    mfma_gram2<<<272, 256, 0, stream>>>(vht, vlt, uht, ult, ws);
    expert_contrib_kernel<<<dim3(128, 4), 256, 0, stream>>>(U, rbf, ws, contrib);
    combine_kernel<<<1024, 256, 0, stream>>>(x, contrib, out);
    finalize_kernel<<<1, 128, 0, stream>>>(ws, out);
}

// Round 7
// 224.288 us; speedup vs baseline: 2.4549x; 1.0562x over previous
//
#include <hip/hip_runtime.h>
#include <math.h>

#define D 512
#define M 128
#define B 16
#define KSEL 4
#define NC 2048           // M*B
#define NTOK 4096         // 2*2048

typedef unsigned short ushort;
typedef unsigned int uint;
typedef __attribute__((ext_vector_type(8))) short short8;   // 8 bf16 (4 VGPRs)
typedef __attribute__((ext_vector_type(4))) float floatx4;  // 4 fp32 acc

// ws layout (float indices)
#define WS_EACC   0       // [128]
#define WS_CACC   128     // [128]
#define WS_VSUM   256     // [1]
#define WS_USUM   257     // [1]
#define WS_CNT_I  258     // int counters [128] (inside zeroed first 512 floats)
#define WS_VSCALE 512     // [2048] 1/||V col||
#define WS_USCALE 2560    // [2048] tanh(us)/||U col||
#define WS_E_F    4608    // [NTOK*M] fp32 energies, 2 MB
#define WS_RBF_F  528896  // R bf16 [NTOK][NC] (16 MB)
#define WS_XH_F   2626048 // xh bf16 [NTOK][D]; REUSED as contrib after gram
#define WS_XL_F   3674624 // xl bf16
#define WS_VHT_F  4723200 // VhT bf16 [NC][D]
#define WS_VLT_F  5247488
#define WS_UHT_F  5771776 // UhT bf16 [NC][D] (col = m*16+b)
#define WS_ULT_F  6296064
#define WS_LIST_F 6820352 // int [128][4096] per-expert token lists, packed (t<<2)|k
                          // end: 7344640 floats = 29.4 MB

// out layout (floats)
#define OUT_TE   2097152
#define OUT_EPE  2097153
#define OUT_RE   2097281
#define OUT_SR   2097409
#define OUT_VPEN 2097537
#define OUT_UPEN 2097538
#define OUT_AUX  2097539

#define GLDS16(g, l) __builtin_amdgcn_global_load_lds(                        \
    (const __attribute__((address_space(1))) unsigned int*)(g),               \
    (__attribute__((address_space(3))) unsigned int*)(l), 16, 0, 0)

__device__ __forceinline__ ushort f2bf(float f) {   // RNE
    union { float f; uint u; } a; a.f = f;
    uint u = a.u;
    u += 0x7fffu + ((u >> 16) & 1u);
    return (ushort)(u >> 16);
}
__device__ __forceinline__ float bf2f(ushort h) {
    union { uint u; float f; } a; a.u = ((uint)h) << 16;
    return a.f;
}

__global__ void convert_x(const float* __restrict__ x, ushort* __restrict__ xh,
                          ushort* __restrict__ xl) {
    const int idx = (blockIdx.x * 256 + threadIdx.x) * 8;
    float4 v0 = *(const float4*)(x + idx);
    float4 v1 = *(const float4*)(x + idx + 4);
    float vv[8] = {v0.x, v0.y, v0.z, v0.w, v1.x, v1.y, v1.z, v1.w};
    union { ushort u[8]; uint4 q; } H, L;
#pragma unroll
    for (int j = 0; j < 8; ++j) {
        ushort h = f2bf(vv[j]);
        H.u[j] = h;
        L.u[j] = f2bf(vv[j] - bf2f(h));
    }
    *(uint4*)(xh + idx) = H.q;
    *(uint4*)(xl + idx) = L.q;
}

__global__ void convert_VT(const float* __restrict__ V, ushort* __restrict__ vht,
                           ushort* __restrict__ vlt) {
    __shared__ float ts[64][65];
    const int tid = threadIdx.x;
    const int col0 = blockIdx.x * 64;
    const int d0 = blockIdx.y * 64;
#pragma unroll
    for (int i = 0; i < 16; ++i) {
        int idx = i * 256 + tid;
        int r = idx >> 6, c = idx & 63;
        ts[r][c] = V[(size_t)(d0 + r) * NC + col0 + c];
    }
    __syncthreads();
#pragma unroll
    for (int i = 0; i < 16; ++i) {
        int idx = i * 256 + tid;
        int c2 = idx >> 6, d2 = idx & 63;
        float v = ts[d2][c2];
        ushort h = f2bf(v);
        vht[(size_t)(col0 + c2) * D + d0 + d2] = h;
        vlt[(size_t)(col0 + c2) * D + d0 + d2] = f2bf(v - bf2f(h));
    }
}

__global__ void convert_UT(const float* __restrict__ U, ushort* __restrict__ uht,
                           ushort* __restrict__ ult) {
    __shared__ float ts[16][129];
    const int tid = threadIdx.x;
    const int m = blockIdx.x;
    for (int d0 = 0; d0 < D; d0 += 128) {
        __syncthreads();
#pragma unroll
        for (int i = 0; i < 8; ++i) {
            int idx = i * 256 + tid;
            int d2 = idx >> 4, b2 = idx & 15;
            ts[b2][d2] = U[(size_t)m * (D * B) + (size_t)(d0 + d2) * B + b2];
        }
        __syncthreads();
#pragma unroll
        for (int i = 0; i < 8; ++i) {
            int idx = i * 256 + tid;
            int b3 = idx >> 7, d3 = idx & 127;
            float v = ts[b3][d3];
            ushort h = f2bf(v);
            uht[(size_t)((m << 4) + b3) * D + d0 + d3] = h;
            ult[(size_t)((m << 4) + b3) * D + d0 + d3] = f2bf(v - bf2f(h));
        }
    }
}

// blocks 0..31: V col norms; 32..159: U expert norms; 160..161: zero ws head.
__global__ void scales_kernel(const float* __restrict__ V,
                              const float* __restrict__ U,
                              const float* __restrict__ us_in,
                              float* __restrict__ ws) {
    const int bx = blockIdx.x;
    const int tid = threadIdx.x;
    if (bx >= 160) {
        ws[(bx - 160) * 256 + tid] = 0.0f;
        return;
    }
    if (bx < 32) {
        const int c = bx * 64 + (tid & 63);
        const int dg = tid >> 6;
        float s = 0.0f;
        for (int d = dg; d < D; d += 4) {
            float v = V[(size_t)d * NC + c];
            s = fmaf(v, v, s);
        }
        __shared__ float sh[4][64];
        sh[dg][tid & 63] = s;
        __syncthreads();
        if (tid < 64) {
            float t = (sh[0][tid] + sh[1][tid]) + (sh[2][tid] + sh[3][tid]);
            ws[WS_VSCALE + bx * 64 + tid] = 1.0f / sqrtf(t);
        }
    } else {
        const int m = bx - 32;
        const float* p = U + (size_t)m * (D * B);
        float s = 0.0f;
        for (int i = tid; i < D * B; i += 256) {
            float v = p[i];
            s = fmaf(v, v, s);
        }
        __shared__ float sh2[256];
        sh2[tid] = s;
        __syncthreads();
        if (tid < 16) {
            float t = 0.0f;
#pragma unroll
            for (int j = 0; j < 16; ++j) t += sh2[tid + (j << 4)];
            ws[WS_USCALE + (m << 4) + tid] = tanhf(us_in[(m << 4) + tid]) / sqrtf(t);
        }
    }
}

// LDS-staged split-bf16 MFMA GEMM: R = (x @ V)*vscale (bf16) + E energies.
__launch_bounds__(256)
__global__ void mfma_gemm(const ushort* __restrict__ xh, const ushort* __restrict__ xl,
                          const ushort* __restrict__ vht, const ushort* __restrict__ vlt,
                          float* __restrict__ ws, ushort* __restrict__ rbf) {
    __shared__ ushort smem[32768];   // 2 bufs x 4 tiles x (128 rows x 32 bf16)
    const int tid = threadIdx.x, lane = tid & 63, w = tid >> 6;
    const int wr = w >> 1, wc = w & 1;
    const int tokB = blockIdx.x * 128, colB = blockIdx.y * 128;
    const int r15 = lane & 15, q = lane >> 4;

    const int srl = lane >> 2;
    const int skq = (lane & 3) ^ ((lane >> 3) & 3);
    const int perm8 = (q ^ ((r15 >> 1) & 3)) * 8;

    floatx4 acc[4][4];
#pragma unroll
    for (int i = 0; i < 4; ++i)
#pragma unroll
        for (int j = 0; j < 4; ++j) acc[i][j] = (floatx4){0.f, 0.f, 0.f, 0.f};

    const ushort* srcs[4] = {xh, xl, vht, vlt};
    const int rbase[4] = {tokB, tokB, colB, colB};

    auto stage = [&](int buf, int c) {
        const int kb = c * 32 + skq * 8;
#pragma unroll
        for (int tI = 0; tI < 4; ++tI) {
            const ushort* s = srcs[tI] + (size_t)rbase[tI] * D + kb;
#pragma unroll
            for (int sub = 0; sub < 2; ++sub) {
                const int row16 = w * 32 + sub * 16;
                GLDS16(s + (size_t)(row16 + srl) * D,
                       &smem[buf * 16384 + tI * 4096 + row16 * 32]);
            }
        }
    };

    stage(0, 0);
    for (int c = 0; c < 16; ++c) {
        __syncthreads();
        if (c < 15) stage((c + 1) & 1, c + 1);
        const ushort* bp = &smem[(c & 1) * 16384];
        short8 ah[4], al[4], bh[4], bl[4];
#pragma unroll
        for (int s = 0; s < 4; ++s) {
            const int ra = (wr * 64 + s * 16 + r15) * 32 + perm8;
            ah[s] = *(const short8*)&bp[ra];
            al[s] = *(const short8*)&bp[4096 + ra];
            const int rb = (wc * 64 + s * 16 + r15) * 32 + perm8;
            bh[s] = *(const short8*)&bp[8192 + rb];
            bl[s] = *(const short8*)&bp[12288 + rb];
        }
#pragma unroll
        for (int st = 0; st < 4; ++st)
#pragma unroll
            for (int sc = 0; sc < 4; ++sc) {
                acc[st][sc] = __builtin_amdgcn_mfma_f32_16x16x32_bf16(ah[st], bh[sc], acc[st][sc], 0, 0, 0);
                acc[st][sc] = __builtin_amdgcn_mfma_f32_16x16x32_bf16(ah[st], bl[sc], acc[st][sc], 0, 0, 0);
                acc[st][sc] = __builtin_amdgcn_mfma_f32_16x16x32_bf16(al[st], bh[sc], acc[st][sc], 0, 0, 0);
            }
    }

    const int tok0 = tokB + wr * 64, col0 = colB + wc * 64;
#pragma unroll
    for (int sc = 0; sc < 4; ++sc) {
        const int colg = col0 + sc * 16 + r15;
        const float vs = ws[WS_VSCALE + colg];
        const int ex = colg >> 4;
#pragma unroll
        for (int st = 0; st < 4; ++st) {
            const int rowb = tok0 + st * 16 + q * 4;
            float r0 = acc[st][sc][0] * vs;
            float r1 = acc[st][sc][1] * vs;
            float r2 = acc[st][sc][2] * vs;
            float r3 = acc[st][sc][3] * vs;
            rbf[(size_t)(rowb + 0) * NC + colg] = f2bf(r0);
            rbf[(size_t)(rowb + 1) * NC + colg] = f2bf(r1);
            rbf[(size_t)(rowb + 2) * NC + colg] = f2bf(r2);
            rbf[(size_t)(rowb + 3) * NC + colg] = f2bf(r3);
            float e0 = r0 * r0, e1 = r1 * r1, e2 = r2 * r2, e3 = r3 * r3;
#pragma unroll
            for (int mk = 1; mk < 16; mk <<= 1) {
                e0 += __shfl_xor(e0, mk);
                e1 += __shfl_xor(e1, mk);
                e2 += __shfl_xor(e2, mk);
                e3 += __shfl_xor(e3, mk);
            }
            if (r15 == 0) {
                float* ep = ws + WS_E_F + (size_t)rowb * M + ex;
                ep[0] = e0; ep[M] = e1; ep[2 * M] = e2; ep[3 * M] = e3;
            }
        }
    }
}

// Merged V+U Gram: 272 blocks; 128x128 tiles over the upper triangle (x2 off-diag).
__launch_bounds__(256)
__global__ void mfma_gram2(const ushort* __restrict__ vht, const ushort* __restrict__ vlt,
                           const ushort* __restrict__ uht, const ushort* __restrict__ ult,
                           float* __restrict__ ws) {
    __shared__ ushort smem[32768];
    int bid = blockIdx.x;
    const int which = bid >= 136;
    int t = which ? bid - 136 : bid;
    int bi = 0, rem = 16;
    while (t >= rem) { t -= rem; --rem; ++bi; }
    const int bj = bi + t;

    const ushort* ht = which ? uht : vht;
    const ushort* lt = which ? ult : vlt;
    const float* scl = ws + (which ? WS_USCALE : WS_VSCALE);
    float* sum_out = ws + (which ? WS_USUM : WS_VSUM);

    const int tid = threadIdx.x, lane = tid & 63, w = tid >> 6;
    const int wr = w >> 1, wc = w & 1;
    const int r15 = lane & 15, q = lane >> 4;
    const int srl = lane >> 2;
    const int skq = (lane & 3) ^ ((lane >> 3) & 3);
    const int perm8 = (q ^ ((r15 >> 1) & 3)) * 8;

    floatx4 acc[4][4];
#pragma unroll
    for (int i = 0; i < 4; ++i)
#pragma unroll
        for (int j = 0; j < 4; ++j) acc[i][j] = (floatx4){0.f, 0.f, 0.f, 0.f};

    const ushort* srcs[4] = {ht, lt, ht, lt};
    const int rbase[4] = {bi * 128, bi * 128, bj * 128, bj * 128};

    auto stage = [&](int buf, int c) {
        const int kb = c * 32 + skq * 8;
#pragma unroll
        for (int tI = 0; tI < 4; ++tI) {
            const ushort* s = srcs[tI] + (size_t)rbase[tI] * D + kb;
#pragma unroll
            for (int sub = 0; sub < 2; ++sub) {
                const int row16 = w * 32 + sub * 16;
                GLDS16(s + (size_t)(row16 + srl) * D,
                       &smem[buf * 16384 + tI * 4096 + row16 * 32]);
            }
        }
    };

    stage(0, 0);
    for (int c = 0; c < 16; ++c) {
        __syncthreads();
        if (c < 15) stage((c + 1) & 1, c + 1);
        const ushort* bp = &smem[(c & 1) * 16384];
        short8 ah[4], al[4], bh[4], bl[4];
#pragma unroll
        for (int s = 0; s < 4; ++s) {
            const int ra = (wr * 64 + s * 16 + r15) * 32 + perm8;
            ah[s] = *(const short8*)&bp[ra];
            al[s] = *(const short8*)&bp[4096 + ra];
            const int rb = (wc * 64 + s * 16 + r15) * 32 + perm8;
            bh[s] = *(const short8*)&bp[8192 + rb];
            bl[s] = *(const short8*)&bp[12288 + rb];
        }
#pragma unroll
        for (int st = 0; st < 4; ++st)
#pragma unroll
            for (int sc = 0; sc < 4; ++sc) {
                acc[st][sc] = __builtin_amdgcn_mfma_f32_16x16x32_bf16(ah[st], bh[sc], acc[st][sc], 0, 0, 0);
                acc[st][sc] = __builtin_amdgcn_mfma_f32_16x16x32_bf16(ah[st], bl[sc], acc[st][sc], 0, 0, 0);
                acc[st][sc] = __builtin_amdgcn_mfma_f32_16x16x32_bf16(al[st], bh[sc], acc[st][sc], 0, 0, 0);
            }
    }

    float local = 0.0f;
#pragma unroll
    for (int sc = 0; sc < 4; ++sc) {
        const int colg = bj * 128 + wc * 64 + sc * 16 + r15;
        const float scj = scl[colg];
#pragma unroll
        for (int st = 0; st < 4; ++st) {
#pragma unroll
            for (int reg = 0; reg < 4; ++reg) {
                const int rowg = bi * 128 + wr * 64 + st * 16 + q * 4 + reg;
                float g = acc[st][sc][reg] * scl[rowg] * scj;
                if (rowg == colg) g -= 1.0f;
                local += fabsf(g);
            }
        }
    }
    if (bi < bj) local *= 2.0f;

#pragma unroll
    for (int mk = 1; mk < 64; mk <<= 1) local += __shfl_xor(local, mk);
    __shared__ float red[4];
    if (lane == 0) red[w] = local;
    __syncthreads();
    if (tid == 0) atomicAdd(sum_out, (red[0] + red[1]) + (red[2] + red[3]));
}

// Wave-parallel top-4: one wave per 4 tokens; butterfly argmax x4 with exact
// jax tie semantics (desc value, lower index wins). No LDS, no divergence.
__launch_bounds__(256)
__global__ void topk_kernel(float* __restrict__ ws) {
    const int tid = threadIdx.x, lane = tid & 63, w = tid >> 6;
    const int tbase = (blockIdx.x * 4 + w) * 4;
    int* icnt = (int*)ws + WS_CNT_I;
    int* ilist = (int*)(ws + WS_LIST_F);

#pragma unroll
    for (int ti = 0; ti < 4; ++ti) {
        const int t = tbase + ti;
        const float2 ev = *(const float2*)(ws + WS_E_F + (size_t)t * M + lane * 2);
        float v0 = ev.x, v1 = ev.y;
        const int i0 = lane * 2, i1 = lane * 2 + 1;

        float bv[4]; int bi[4];
#pragma unroll
        for (int r = 0; r < 4; ++r) {
            float cv; int ci;
            if (v0 >= v1) { cv = v0; ci = i0; } else { cv = v1; ci = i1; }
#pragma unroll
            for (int mk = 1; mk < 64; mk <<= 1) {
                float ov = __shfl_xor(cv, mk);
                int oi = __shfl_xor(ci, mk);
                if (ov > cv || (ov == cv && oi < ci)) { cv = ov; ci = oi; }
            }
            bv[r] = cv; bi[r] = ci;
            if (ci == i0) v0 = -1e30f;
            if (ci == i1) v1 = -1e30f;
        }

        if (lane < 4) {
            const int e = bi[lane];
            atomicAdd(&ws[WS_EACC + e], bv[lane]);
            atomicAdd(&ws[WS_CACC + e], 1.0f);
            int pos = atomicAdd(&icnt[e], 1);
            ilist[(e << 12) + pos] = (t << 2) | lane;
        }
    }
}

// Expert-major contributions: contrib[t][k][d] (bf16 pairs packed in uint).
__launch_bounds__(256)
__global__ void expert_contrib_kernel(const float* __restrict__ U,
                                      const ushort* __restrict__ rbf,
                                      const float* __restrict__ ws,
                                      uint* __restrict__ contrib) {
    const int e = blockIdx.x;
    const int tid = threadIdx.x;
    const int cnt = ((const int*)ws)[WS_CNT_I + e];
    if ((int)blockIdx.y >= cnt) return;

    float usc[16];
#pragma unroll
    for (int b = 0; b < 16; ++b) usc[b] = ws[WS_USCALE + (e << 4) + b];

    const float* Up = U + (size_t)e * (D * B);
    float u0[16], u1[16];
#pragma unroll
    for (int qd = 0; qd < 4; ++qd) {
        float4 a = *(const float4*)(Up + (size_t)(2 * tid) * B + qd * 4);
        float4 b4 = *(const float4*)(Up + (size_t)(2 * tid + 1) * B + qd * 4);
        u0[qd * 4 + 0] = a.x * usc[qd * 4 + 0];
        u0[qd * 4 + 1] = a.y * usc[qd * 4 + 1];
        u0[qd * 4 + 2] = a.z * usc[qd * 4 + 2];
        u0[qd * 4 + 3] = a.w * usc[qd * 4 + 3];
        u1[qd * 4 + 0] = b4.x * usc[qd * 4 + 0];
        u1[qd * 4 + 1] = b4.y * usc[qd * 4 + 1];
        u1[qd * 4 + 2] = b4.z * usc[qd * 4 + 2];
        u1[qd * 4 + 3] = b4.w * usc[qd * 4 + 3];
    }

    const int* ilist = (const int*)(ws + WS_LIST_F) + (e << 12);
    int i = blockIdx.y;
    int pk = (i < cnt) ? ilist[i] : 0;
    while (i < cnt) {
        const int t = pk >> 2, k = pk & 3;
        const ushort* rp = rbf + (size_t)t * NC + (e << 4);
        union { ushort u[16]; uint4 q[2]; } R;
        R.q[0] = *(const uint4*)(rp);
        R.q[1] = *(const uint4*)(rp + 8);
        const int inext = i + 4;
        if (inext < cnt) pk = ilist[inext];
        float acc0 = 0.0f, acc1 = 0.0f;
#pragma unroll
        for (int b = 0; b < 16; ++b) {
            const float wv = bf2f(R.u[b]);
            acc0 = fmaf(u0[b], wv, acc0);
            acc1 = fmaf(u1[b], wv, acc1);
        }
        contrib[(size_t)((t << 2) + k) * 256 + tid] =
            (uint)f2bf(acc0) | ((uint)f2bf(acc1) << 16);
        i = inext;
    }
}

// out[t][d] = x[t][d] + sum_k contrib[t][k][d]  (streaming, coalesced)
__launch_bounds__(256)
__global__ void combine_kernel(const float* __restrict__ x,
                               const uint* __restrict__ contrib,
                               float* __restrict__ out) {
    const int gid = blockIdx.x * 256 + threadIdx.x;
    const int t = gid >> 6;
    const int dq = (gid & 63) << 3;
    const uint4* cp = (const uint4*)contrib;

    float s[8];
    float4 x0 = *(const float4*)(x + (size_t)t * D + dq);
    float4 x1 = *(const float4*)(x + (size_t)t * D + dq + 4);
    s[0] = x0.x; s[1] = x0.y; s[2] = x0.z; s[3] = x0.w;
    s[4] = x1.x; s[5] = x1.y; s[6] = x1.z; s[7] = x1.w;
#pragma unroll
    for (int k = 0; k < KSEL; ++k) {
        uint4 cvec = cp[(size_t)((t << 2) + k) * 64 + (dq >> 3)];
        uint cc[4] = {cvec.x, cvec.y, cvec.z, cvec.w};
#pragma unroll
        for (int j = 0; j < 4; ++j) {
            s[2 * j]     += bf2f((ushort)(cc[j] & 0xffffu));
            s[2 * j + 1] += bf2f((ushort)(cc[j] >> 16));
        }
    }
    float* op = out + (size_t)t * D + dq;
    *(float4*)(op)     = make_float4(s[0], s[1], s[2], s[3]);
    *(float4*)(op + 4) = make_float4(s[4], s[5], s[6], s[7]);
}

__global__ void finalize_kernel(const float* __restrict__ ws, float* __restrict__ out) {
    const int m = threadIdx.x;   // 128 threads
    float e = ws[WS_EACC + m] * (1.0f / (float)NTOK);
    float c = ws[WS_CACC + m] * (1.0f / (float)NTOK);

    float s = e;
#pragma unroll
    for (int off = 32; off > 0; off >>= 1) s += __shfl_down(s, off);
    __shared__ float sh[2];
    if ((m & 63) == 0) sh[m >> 6] = s;
    __syncthreads();
    float total = sh[0] + sh[1];
    float total_energy = fmaxf(total, 1e-12f);

    out[OUT_EPE + m] = e;
    out[OUT_RE + m] = e / total_energy;
    out[OUT_SR + m] = c;
    if (m == 0) {
        out[OUT_TE] = total_energy;
        float inv_n2 = 1.0f / ((float)NC * (float)NC);
        float sqrtD = sqrtf((float)D);
        float vpen = ws[WS_VSUM] * inv_n2 * sqrtD;
        float upen = ws[WS_USUM] * inv_n2 * sqrtD;
        out[OUT_VPEN] = vpen;
        out[OUT_UPEN] = upen;
        out[OUT_AUX] = 0.01f * vpen - total_energy;
    }
}

extern "C" void kernel_launch(void* const* d_in, const int* in_sizes, int n_in,
                              void* d_out, int out_size, void* d_ws, size_t ws_size,
                              hipStream_t stream) {
    const float* x  = (const float*)d_in[0];
    const float* V  = (const float*)d_in[1];
    const float* U  = (const float*)d_in[2];
    const float* us = (const float*)d_in[3];
    float* out = (float*)d_out;
    float* ws  = (float*)d_ws;

    ushort* xh  = (ushort*)(ws + WS_XH_F);
    ushort* xl  = (ushort*)(ws + WS_XL_F);
    ushort* vht = (ushort*)(ws + WS_VHT_F);
    ushort* vlt = (ushort*)(ws + WS_VLT_F);
    ushort* uht = (ushort*)(ws + WS_UHT_F);
    ushort* ult = (ushort*)(ws + WS_ULT_F);
    ushort* rbf = (ushort*)(ws + WS_RBF_F);
    uint* contrib = (uint*)(ws + WS_XH_F);   // reuses xh..ult after gram

    convert_x<<<1024, 256, 0, stream>>>(x, xh, xl);
    convert_VT<<<dim3(32, 8), 256, 0, stream>>>(V, vht, vlt);
    convert_UT<<<128, 256, 0, stream>>>(U, uht, ult);
    scales_kernel<<<162, 256, 0, stream>>>(V, U, us, ws);
    mfma_gemm<<<dim3(32, 16), 256, 0, stream>>>(xh, xl, vht, vlt, ws, rbf);
    topk_kernel<<<NTOK / 16, 256, 0, stream>>>(ws);
    mfma_gram2<<<272, 256, 0, stream>>>(vht, vlt, uht, ult, ws);
    expert_contrib_kernel<<<dim3(128, 4), 256, 0, stream>>>(U, rbf, ws, contrib);
    combine_kernel<<<1024, 256, 0, stream>>>(x, contrib, out);
    finalize_kernel<<<1, 128, 0, stream>>>(ws, out);
}

// Round 8
// 221.251 us; speedup vs baseline: 2.4886x; 1.0137x over previous
//
#include <hip/hip_runtime.h>
#include <math.h>

#define D 512
#define M 128
#define B 16
#define KSEL 4
#define NC 2048           // M*B
#define NTOK 4096         // 2*2048

typedef unsigned short ushort;
typedef unsigned int uint;
typedef unsigned long long u64;
typedef __attribute__((ext_vector_type(8))) short short8;   // 8 bf16 (4 VGPRs)
typedef __attribute__((ext_vector_type(4))) float floatx4;  // 4 fp32 acc

// ws layout (float indices)
#define WS_EACC   0       // [128]
#define WS_CACC   128     // [128]
#define WS_VSUM   256     // [1]
#define WS_USUM   257     // [1]
#define WS_CNT_I  258     // int counters [128] (inside zeroed first 512 floats)
#define WS_VSCALE 512     // [2048] 1/||V col||
#define WS_USCALE 2560    // [2048] tanh(us)/||U col||
#define WS_E_F    4608    // [NTOK*M] fp32 energies, 2 MB
#define WS_RBF_F  528896  // R bf16 [NTOK][NC] (16 MB)
#define WS_XH_F   2626048 // xh bf16 [NTOK][D]; REUSED as contrib after gram
#define WS_XL_F   3674624 // xl bf16
#define WS_VHT_F  4723200 // VhT bf16 [NC][D]
#define WS_VLT_F  5247488
#define WS_UHT_F  5771776 // UhT bf16 [NC][D] (col = m*16+b)
#define WS_ULT_F  6296064
#define WS_LIST_F 6820352 // int [128][4096] per-expert token lists, packed (t<<2)|k
                          // end: 7344640 floats = 29.4 MB

// out layout (floats)
#define OUT_TE   2097152
#define OUT_EPE  2097153
#define OUT_RE   2097281
#define OUT_SR   2097409
#define OUT_VPEN 2097537
#define OUT_UPEN 2097538
#define OUT_AUX  2097539

#define GLDS16(g, l) __builtin_amdgcn_global_load_lds(                        \
    (const __attribute__((address_space(1))) unsigned int*)(g),               \
    (__attribute__((address_space(3))) unsigned int*)(l), 16, 0, 0)

__device__ __forceinline__ ushort f2bf(float f) {   // RNE
    union { float f; uint u; } a; a.f = f;
    uint u = a.u;
    u += 0x7fffu + ((u >> 16) & 1u);
    return (ushort)(u >> 16);
}
__device__ __forceinline__ float bf2f(ushort h) {
    union { uint u; float f; } a; a.u = ((uint)h) << 16;
    return a.f;
}

__global__ void convert_x(const float* __restrict__ x, ushort* __restrict__ xh,
                          ushort* __restrict__ xl) {
    const int idx = (blockIdx.x * 256 + threadIdx.x) * 8;
    float4 v0 = *(const float4*)(x + idx);
    float4 v1 = *(const float4*)(x + idx + 4);
    float vv[8] = {v0.x, v0.y, v0.z, v0.w, v1.x, v1.y, v1.z, v1.w};
    union { ushort u[8]; uint4 q; } H, L;
#pragma unroll
    for (int j = 0; j < 8; ++j) {
        ushort h = f2bf(vv[j]);
        H.u[j] = h;
        L.u[j] = f2bf(vv[j] - bf2f(h));
    }
    *(uint4*)(xh + idx) = H.q;
    *(uint4*)(xl + idx) = L.q;
}

__global__ void convert_VT(const float* __restrict__ V, ushort* __restrict__ vht,
                           ushort* __restrict__ vlt) {
    __shared__ float ts[64][65];
    const int tid = threadIdx.x;
    const int col0 = blockIdx.x * 64;
    const int d0 = blockIdx.y * 64;
#pragma unroll
    for (int i = 0; i < 16; ++i) {
        int idx = i * 256 + tid;
        int r = idx >> 6, c = idx & 63;
        ts[r][c] = V[(size_t)(d0 + r) * NC + col0 + c];
    }
    __syncthreads();
#pragma unroll
    for (int i = 0; i < 16; ++i) {
        int idx = i * 256 + tid;
        int c2 = idx >> 6, d2 = idx & 63;
        float v = ts[d2][c2];
        ushort h = f2bf(v);
        vht[(size_t)(col0 + c2) * D + d0 + d2] = h;
        vlt[(size_t)(col0 + c2) * D + d0 + d2] = f2bf(v - bf2f(h));
    }
}

__global__ void convert_UT(const float* __restrict__ U, ushort* __restrict__ uht,
                           ushort* __restrict__ ult) {
    __shared__ float ts[16][129];
    const int tid = threadIdx.x;
    const int m = blockIdx.x;
    for (int d0 = 0; d0 < D; d0 += 128) {
        __syncthreads();
#pragma unroll
        for (int i = 0; i < 8; ++i) {
            int idx = i * 256 + tid;
            int d2 = idx >> 4, b2 = idx & 15;
            ts[b2][d2] = U[(size_t)m * (D * B) + (size_t)(d0 + d2) * B + b2];
        }
        __syncthreads();
#pragma unroll
        for (int i = 0; i < 8; ++i) {
            int idx = i * 256 + tid;
            int b3 = idx >> 7, d3 = idx & 127;
            float v = ts[b3][d3];
            ushort h = f2bf(v);
            uht[(size_t)((m << 4) + b3) * D + d0 + d3] = h;
            ult[(size_t)((m << 4) + b3) * D + d0 + d3] = f2bf(v - bf2f(h));
        }
    }
}

// blocks 0..31: V col norms; 32..159: U expert norms; 160..161: zero ws head.
__global__ void scales_kernel(const float* __restrict__ V,
                              const float* __restrict__ U,
                              const float* __restrict__ us_in,
                              float* __restrict__ ws) {
    const int bx = blockIdx.x;
    const int tid = threadIdx.x;
    if (bx >= 160) {
        ws[(bx - 160) * 256 + tid] = 0.0f;
        return;
    }
    if (bx < 32) {
        const int c = bx * 64 + (tid & 63);
        const int dg = tid >> 6;
        float s = 0.0f;
        for (int d = dg; d < D; d += 4) {
            float v = V[(size_t)d * NC + c];
            s = fmaf(v, v, s);
        }
        __shared__ float sh[4][64];
        sh[dg][tid & 63] = s;
        __syncthreads();
        if (tid < 64) {
            float t = (sh[0][tid] + sh[1][tid]) + (sh[2][tid] + sh[3][tid]);
            ws[WS_VSCALE + bx * 64 + tid] = 1.0f / sqrtf(t);
        }
    } else {
        const int m = bx - 32;
        const float* p = U + (size_t)m * (D * B);
        float s = 0.0f;
        for (int i = tid; i < D * B; i += 256) {
            float v = p[i];
            s = fmaf(v, v, s);
        }
        __shared__ float sh2[256];
        sh2[tid] = s;
        __syncthreads();
        if (tid < 16) {
            float t = 0.0f;
#pragma unroll
            for (int j = 0; j < 16; ++j) t += sh2[tid + (j << 4)];
            ws[WS_USCALE + (m << 4) + tid] = tanhf(us_in[(m << 4) + tid]) / sqrtf(t);
        }
    }
}

// LDS-staged split-bf16 MFMA GEMM: R = (x @ V)*vscale (bf16) + E energies.
__launch_bounds__(256)
__global__ void mfma_gemm(const ushort* __restrict__ xh, const ushort* __restrict__ xl,
                          const ushort* __restrict__ vht, const ushort* __restrict__ vlt,
                          float* __restrict__ ws, ushort* __restrict__ rbf) {
    __shared__ ushort smem[32768];   // 2 bufs x 4 tiles x (128 rows x 32 bf16)
    const int tid = threadIdx.x, lane = tid & 63, w = tid >> 6;
    const int wr = w >> 1, wc = w & 1;
    const int tokB = blockIdx.x * 128, colB = blockIdx.y * 128;
    const int r15 = lane & 15, q = lane >> 4;

    const int srl = lane >> 2;
    const int skq = (lane & 3) ^ ((lane >> 3) & 3);
    const int perm8 = (q ^ ((r15 >> 1) & 3)) * 8;

    floatx4 acc[4][4];
#pragma unroll
    for (int i = 0; i < 4; ++i)
#pragma unroll
        for (int j = 0; j < 4; ++j) acc[i][j] = (floatx4){0.f, 0.f, 0.f, 0.f};

    const ushort* srcs[4] = {xh, xl, vht, vlt};
    const int rbase[4] = {tokB, tokB, colB, colB};

    auto stage = [&](int buf, int c) {
        const int kb = c * 32 + skq * 8;
#pragma unroll
        for (int tI = 0; tI < 4; ++tI) {
            const ushort* s = srcs[tI] + (size_t)rbase[tI] * D + kb;
#pragma unroll
            for (int sub = 0; sub < 2; ++sub) {
                const int row16 = w * 32 + sub * 16;
                GLDS16(s + (size_t)(row16 + srl) * D,
                       &smem[buf * 16384 + tI * 4096 + row16 * 32]);
            }
        }
    };

    stage(0, 0);
    for (int c = 0; c < 16; ++c) {
        __syncthreads();
        if (c < 15) stage((c + 1) & 1, c + 1);
        const ushort* bp = &smem[(c & 1) * 16384];
        short8 ah[4], al[4], bh[4], bl[4];
#pragma unroll
        for (int s = 0; s < 4; ++s) {
            const int ra = (wr * 64 + s * 16 + r15) * 32 + perm8;
            ah[s] = *(const short8*)&bp[ra];
            al[s] = *(const short8*)&bp[4096 + ra];
            const int rb = (wc * 64 + s * 16 + r15) * 32 + perm8;
            bh[s] = *(const short8*)&bp[8192 + rb];
            bl[s] = *(const short8*)&bp[12288 + rb];
        }
#pragma unroll
        for (int st = 0; st < 4; ++st)
#pragma unroll
            for (int sc = 0; sc < 4; ++sc) {
                acc[st][sc] = __builtin_amdgcn_mfma_f32_16x16x32_bf16(ah[st], bh[sc], acc[st][sc], 0, 0, 0);
                acc[st][sc] = __builtin_amdgcn_mfma_f32_16x16x32_bf16(ah[st], bl[sc], acc[st][sc], 0, 0, 0);
                acc[st][sc] = __builtin_amdgcn_mfma_f32_16x16x32_bf16(al[st], bh[sc], acc[st][sc], 0, 0, 0);
            }
    }

    const int tok0 = tokB + wr * 64, col0 = colB + wc * 64;
#pragma unroll
    for (int sc = 0; sc < 4; ++sc) {
        const int colg = col0 + sc * 16 + r15;
        const float vs = ws[WS_VSCALE + colg];
        const int ex = colg >> 4;
#pragma unroll
        for (int st = 0; st < 4; ++st) {
            const int rowb = tok0 + st * 16 + q * 4;
            float r0 = acc[st][sc][0] * vs;
            float r1 = acc[st][sc][1] * vs;
            float r2 = acc[st][sc][2] * vs;
            float r3 = acc[st][sc][3] * vs;
            rbf[(size_t)(rowb + 0) * NC + colg] = f2bf(r0);
            rbf[(size_t)(rowb + 1) * NC + colg] = f2bf(r1);
            rbf[(size_t)(rowb + 2) * NC + colg] = f2bf(r2);
            rbf[(size_t)(rowb + 3) * NC + colg] = f2bf(r3);
            float e0 = r0 * r0, e1 = r1 * r1, e2 = r2 * r2, e3 = r3 * r3;
#pragma unroll
            for (int mk = 1; mk < 16; mk <<= 1) {
                e0 += __shfl_xor(e0, mk);
                e1 += __shfl_xor(e1, mk);
                e2 += __shfl_xor(e2, mk);
                e3 += __shfl_xor(e3, mk);
            }
            if (r15 == 0) {
                float* ep = ws + WS_E_F + (size_t)rowb * M + ex;
                ep[0] = e0; ep[M] = e1; ep[2 * M] = e2; ep[3 * M] = e3;
            }
        }
    }
}

// Merged V+U Gram: 272 blocks; 128x128 tiles over the upper triangle (x2 off-diag).
__launch_bounds__(256)
__global__ void mfma_gram2(const ushort* __restrict__ vht, const ushort* __restrict__ vlt,
                           const ushort* __restrict__ uht, const ushort* __restrict__ ult,
                           float* __restrict__ ws) {
    __shared__ ushort smem[32768];
    int bid = blockIdx.x;
    const int which = bid >= 136;
    int t = which ? bid - 136 : bid;
    int bi = 0, rem = 16;
    while (t >= rem) { t -= rem; --rem; ++bi; }
    const int bj = bi + t;

    const ushort* ht = which ? uht : vht;
    const ushort* lt = which ? ult : vlt;
    const float* scl = ws + (which ? WS_USCALE : WS_VSCALE);
    float* sum_out = ws + (which ? WS_USUM : WS_VSUM);

    const int tid = threadIdx.x, lane = tid & 63, w = tid >> 6;
    const int wr = w >> 1, wc = w & 1;
    const int r15 = lane & 15, q = lane >> 4;
    const int srl = lane >> 2;
    const int skq = (lane & 3) ^ ((lane >> 3) & 3);
    const int perm8 = (q ^ ((r15 >> 1) & 3)) * 8;

    floatx4 acc[4][4];
#pragma unroll
    for (int i = 0; i < 4; ++i)
#pragma unroll
        for (int j = 0; j < 4; ++j) acc[i][j] = (floatx4){0.f, 0.f, 0.f, 0.f};

    const ushort* srcs[4] = {ht, lt, ht, lt};
    const int rbase[4] = {bi * 128, bi * 128, bj * 128, bj * 128};

    auto stage = [&](int buf, int c) {
        const int kb = c * 32 + skq * 8;
#pragma unroll
        for (int tI = 0; tI < 4; ++tI) {
            const ushort* s = srcs[tI] + (size_t)rbase[tI] * D + kb;
#pragma unroll
            for (int sub = 0; sub < 2; ++sub) {
                const int row16 = w * 32 + sub * 16;
                GLDS16(s + (size_t)(row16 + srl) * D,
                       &smem[buf * 16384 + tI * 4096 + row16 * 32]);
            }
        }
    };

    stage(0, 0);
    for (int c = 0; c < 16; ++c) {
        __syncthreads();
        if (c < 15) stage((c + 1) & 1, c + 1);
        const ushort* bp = &smem[(c & 1) * 16384];
        short8 ah[4], al[4], bh[4], bl[4];
#pragma unroll
        for (int s = 0; s < 4; ++s) {
            const int ra = (wr * 64 + s * 16 + r15) * 32 + perm8;
            ah[s] = *(const short8*)&bp[ra];
            al[s] = *(const short8*)&bp[4096 + ra];
            const int rb = (wc * 64 + s * 16 + r15) * 32 + perm8;
            bh[s] = *(const short8*)&bp[8192 + rb];
            bl[s] = *(const short8*)&bp[12288 + rb];
        }
#pragma unroll
        for (int st = 0; st < 4; ++st)
#pragma unroll
            for (int sc = 0; sc < 4; ++sc) {
                acc[st][sc] = __builtin_amdgcn_mfma_f32_16x16x32_bf16(ah[st], bh[sc], acc[st][sc], 0, 0, 0);
                acc[st][sc] = __builtin_amdgcn_mfma_f32_16x16x32_bf16(ah[st], bl[sc], acc[st][sc], 0, 0, 0);
                acc[st][sc] = __builtin_amdgcn_mfma_f32_16x16x32_bf16(al[st], bh[sc], acc[st][sc], 0, 0, 0);
            }
    }

    float local = 0.0f;
#pragma unroll
    for (int sc = 0; sc < 4; ++sc) {
        const int colg = bj * 128 + wc * 64 + sc * 16 + r15;
        const float scj = scl[colg];
#pragma unroll
        for (int st = 0; st < 4; ++st) {
#pragma unroll
            for (int reg = 0; reg < 4; ++reg) {
                const int rowg = bi * 128 + wr * 64 + st * 16 + q * 4 + reg;
                float g = acc[st][sc][reg] * scl[rowg] * scj;
                if (rowg == colg) g -= 1.0f;
                local += fabsf(g);
            }
        }
    }
    if (bi < bj) local *= 2.0f;

#pragma unroll
    for (int mk = 1; mk < 64; mk <<= 1) local += __shfl_xor(local, mk);
    __shared__ float red[4];
    if (lane == 0) red[w] = local;
    __syncthreads();
    if (tid == 0) atomicAdd(sum_out, (red[0] + red[1]) + (red[2] + red[3]));
}

// Wave-per-token top-4: packed u64 keys (val_bits<<32 | ~idx — exact jax tie
// order), sorted-quadruple butterfly: 6 steps, each = bitonic halver + 4-sort.
__launch_bounds__(256)
__global__ void topk_kernel(float* __restrict__ ws) {
    const int tid = threadIdx.x, lane = tid & 63, w = tid >> 6;
    const int t = blockIdx.x * 4 + w;
    int* icnt = (int*)ws + WS_CNT_I;
    int* ilist = (int*)(ws + WS_LIST_F);

    const float2 ev = *(const float2*)(ws + WS_E_F + (size_t)t * M + lane * 2);
    const uint i0 = (uint)(lane * 2), i1 = i0 + 1;
    u64 k0 = ((u64)__float_as_uint(ev.x) << 32) | (uint)(~i0);
    u64 k1 = ((u64)__float_as_uint(ev.y) << 32) | (uint)(~i1);
    u64 s0 = k0 > k1 ? k0 : k1;
    u64 s1 = k0 > k1 ? k1 : k0;
    u64 s2 = 0, s3 = 0;

#pragma unroll
    for (int mk = 1; mk < 64; mk <<= 1) {
        u64 o0 = __shfl_xor(s0, mk);
        u64 o1 = __shfl_xor(s1, mk);
        u64 o2 = __shfl_xor(s2, mk);
        u64 o3 = __shfl_xor(s3, mk);
        // bitonic halver: top-4 multiset of the 8
        u64 c0 = s0 > o3 ? s0 : o3;
        u64 c1 = s1 > o2 ? s1 : o2;
        u64 c2 = s2 > o1 ? s2 : o1;
        u64 c3 = s3 > o0 ? s3 : o0;
        // bitonic sort desc: CE(0,2),(1,3) then CE(0,1),(2,3)
        u64 d0 = c0 > c2 ? c0 : c2, d2 = c0 > c2 ? c2 : c0;
        u64 d1 = c1 > c3 ? c1 : c3, d3 = c1 > c3 ? c3 : c1;
        s0 = d0 > d1 ? d0 : d1; s1 = d0 > d1 ? d1 : d0;
        s2 = d2 > d3 ? d2 : d3; s3 = d2 > d3 ? d3 : d2;
    }

    if (lane < 4) {
        u64 key = (lane == 0) ? s0 : (lane == 1) ? s1 : (lane == 2) ? s2 : s3;
        const int e = (int)(~(uint)key);
        const float val = __uint_as_float((uint)(key >> 32));
        atomicAdd(&ws[WS_EACC + e], val);
        atomicAdd(&ws[WS_CACC + e], 1.0f);
        int pos = atomicAdd(&icnt[e], 1);
        ilist[(e << 12) + pos] = (t << 2) | lane;
    }
}

// Expert-major contributions: contrib[t][k][d] (bf16 pairs packed in uint).
__launch_bounds__(256)
__global__ void expert_contrib_kernel(const float* __restrict__ U,
                                      const ushort* __restrict__ rbf,
                                      const float* __restrict__ ws,
                                      uint* __restrict__ contrib) {
    const int e = blockIdx.x;
    const int tid = threadIdx.x;
    const int cnt = ((const int*)ws)[WS_CNT_I + e];
    if ((int)blockIdx.y >= cnt) return;

    float usc[16];
#pragma unroll
    for (int b = 0; b < 16; ++b) usc[b] = ws[WS_USCALE + (e << 4) + b];

    const float* Up = U + (size_t)e * (D * B);
    float u0[16], u1[16];
#pragma unroll
    for (int qd = 0; qd < 4; ++qd) {
        float4 a = *(const float4*)(Up + (size_t)(2 * tid) * B + qd * 4);
        float4 b4 = *(const float4*)(Up + (size_t)(2 * tid + 1) * B + qd * 4);
        u0[qd * 4 + 0] = a.x * usc[qd * 4 + 0];
        u0[qd * 4 + 1] = a.y * usc[qd * 4 + 1];
        u0[qd * 4 + 2] = a.z * usc[qd * 4 + 2];
        u0[qd * 4 + 3] = a.w * usc[qd * 4 + 3];
        u1[qd * 4 + 0] = b4.x * usc[qd * 4 + 0];
        u1[qd * 4 + 1] = b4.y * usc[qd * 4 + 1];
        u1[qd * 4 + 2] = b4.z * usc[qd * 4 + 2];
        u1[qd * 4 + 3] = b4.w * usc[qd * 4 + 3];
    }

    const int* ilist = (const int*)(ws + WS_LIST_F) + (e << 12);
    int i = blockIdx.y;
    int pk = (i < cnt) ? ilist[i] : 0;
    while (i < cnt) {
        const int t = pk >> 2, k = pk & 3;
        const ushort* rp = rbf + (size_t)t * NC + (e << 4);
        union { ushort u[16]; uint4 q[2]; } R;
        R.q[0] = *(const uint4*)(rp);
        R.q[1] = *(const uint4*)(rp + 8);
        const int inext = i + 4;
        if (inext < cnt) pk = ilist[inext];
        float acc0 = 0.0f, acc1 = 0.0f;
#pragma unroll
        for (int b = 0; b < 16; ++b) {
            const float wv = bf2f(R.u[b]);
            acc0 = fmaf(u0[b], wv, acc0);
            acc1 = fmaf(u1[b], wv, acc1);
        }
        contrib[(size_t)((t << 2) + k) * 256 + tid] =
            (uint)f2bf(acc0) | ((uint)f2bf(acc1) << 16);
        i = inext;
    }
}

// out[t][d] = x[t][d] + sum_k contrib[t][k][d]  (streaming, coalesced)
__launch_bounds__(256)
__global__ void combine_kernel(const float* __restrict__ x,
                               const uint* __restrict__ contrib,
                               float* __restrict__ out) {
    const int gid = blockIdx.x * 256 + threadIdx.x;
    const int t = gid >> 6;
    const int dq = (gid & 63) << 3;
    const uint4* cp = (const uint4*)contrib;

    float s[8];
    float4 x0 = *(const float4*)(x + (size_t)t * D + dq);
    float4 x1 = *(const float4*)(x + (size_t)t * D + dq + 4);
    s[0] = x0.x; s[1] = x0.y; s[2] = x0.z; s[3] = x0.w;
    s[4] = x1.x; s[5] = x1.y; s[6] = x1.z; s[7] = x1.w;
#pragma unroll
    for (int k = 0; k < KSEL; ++k) {
        uint4 cvec = cp[(size_t)((t << 2) + k) * 64 + (dq >> 3)];
        uint cc[4] = {cvec.x, cvec.y, cvec.z, cvec.w};
#pragma unroll
        for (int j = 0; j < 4; ++j) {
            s[2 * j]     += bf2f((ushort)(cc[j] & 0xffffu));
            s[2 * j + 1] += bf2f((ushort)(cc[j] >> 16));
        }
    }
    float* op = out + (size_t)t * D + dq;
    *(float4*)(op)     = make_float4(s[0], s[1], s[2], s[3]);
    *(float4*)(op + 4) = make_float4(s[4], s[5], s[6], s[7]);
}

__global__ void finalize_kernel(const float* __restrict__ ws, float* __restrict__ out) {
    const int m = threadIdx.x;   // 128 threads
    float e = ws[WS_EACC + m] * (1.0f / (float)NTOK);
    float c = ws[WS_CACC + m] * (1.0f / (float)NTOK);

    float s = e;
#pragma unroll
    for (int off = 32; off > 0; off >>= 1) s += __shfl_down(s, off);
    __shared__ float sh[2];
    if ((m & 63) == 0) sh[m >> 6] = s;
    __syncthreads();
    float total = sh[0] + sh[1];
    float total_energy = fmaxf(total, 1e-12f);

    out[OUT_EPE + m] = e;
    out[OUT_RE + m] = e / total_energy;
    out[OUT_SR + m] = c;
    if (m == 0) {
        out[OUT_TE] = total_energy;
        float inv_n2 = 1.0f / ((float)NC * (float)NC);
        float sqrtD = sqrtf((float)D);
        float vpen = ws[WS_VSUM] * inv_n2 * sqrtD;
        float upen = ws[WS_USUM] * inv_n2 * sqrtD;
        out[OUT_VPEN] = vpen;
        out[OUT_UPEN] = upen;
        out[OUT_AUX] = 0.01f * vpen - total_energy;
    }
}

extern "C" void kernel_launch(void* const* d_in, const int* in_sizes, int n_in,
                              void* d_out, int out_size, void* d_ws, size_t ws_size,
                              hipStream_t stream) {
    const float* x  = (const float*)d_in[0];
    const float* V  = (const float*)d_in[1];
    const float* U  = (const float*)d_in[2];
    const float* us = (const float*)d_in[3];
    float* out = (float*)d_out;
    float* ws  = (float*)d_ws;

    ushort* xh  = (ushort*)(ws + WS_XH_F);
    ushort* xl  = (ushort*)(ws + WS_XL_F);
    ushort* vht = (ushort*)(ws + WS_VHT_F);
    ushort* vlt = (ushort*)(ws + WS_VLT_F);
    ushort* uht = (ushort*)(ws + WS_UHT_F);
    ushort* ult = (ushort*)(ws + WS_ULT_F);
    ushort* rbf = (ushort*)(ws + WS_RBF_F);
    uint* contrib = (uint*)(ws + WS_XH_F);   // reuses xh..ult after gram

    convert_x<<<1024, 256, 0, stream>>>(x, xh, xl);
    convert_VT<<<dim3(32, 8), 256, 0, stream>>>(V, vht, vlt);
    convert_UT<<<128, 256, 0, stream>>>(U, uht, ult);
    scales_kernel<<<162, 256, 0, stream>>>(V, U, us, ws);
    mfma_gemm<<<dim3(32, 16), 256, 0, stream>>>(xh, xl, vht, vlt, ws, rbf);
    topk_kernel<<<NTOK / 4, 256, 0, stream>>>(ws);
    mfma_gram2<<<272, 256, 0, stream>>>(vht, vlt, uht, ult, ws);
    expert_contrib_kernel<<<dim3(128, 4), 256, 0, stream>>>(U, rbf, ws, contrib);
    combine_kernel<<<1024, 256, 0, stream>>>(x, contrib, out);
    finalize_kernel<<<1, 128, 0, stream>>>(ws, out);
}

// Round 9
// 208.743 us; speedup vs baseline: 2.6377x; 1.0599x over previous
//
#include <hip/hip_runtime.h>
#include <math.h>

#define D 512
#define M 128
#define B 16
#define KSEL 4
#define NC 2048           // M*B
#define NTOK 4096         // 2*2048

typedef unsigned short ushort;
typedef unsigned int uint;
typedef unsigned long long u64;
typedef __attribute__((ext_vector_type(8))) short short8;   // 8 bf16 (4 VGPRs)
typedef __attribute__((ext_vector_type(4))) float floatx4;  // 4 fp32 acc

// ws layout (float indices)
#define WS_EACC   0       // [128]
#define WS_CACC   128     // [128]
#define WS_VSUM   256     // [1]
#define WS_USUM   257     // [1]
#define WS_CNT_I  258     // int counters [128] (inside zeroed first 512 floats)
#define WS_VSCALE 512     // [2048] 1/||V col||
#define WS_USCALE 2560    // [2048] tanh(us)/||U col||
#define WS_E_F    4608    // [NTOK*M] fp32 energies, 2 MB
#define WS_RBF_F  528896  // R bf16 [NTOK][NC] (16 MB)
#define WS_XH_F   2626048 // xh bf16 [NTOK][D]; REUSED as contrib after gram
#define WS_XL_F   3674624 // xl bf16
#define WS_VHT_F  4723200 // VhT bf16 [NC][D]
#define WS_VLT_F  5247488
#define WS_UHT_F  5771776 // UhT bf16 [NC][D] (col = m*16+b)
#define WS_ULT_F  6296064
#define WS_LIST_F 6820352 // int [128][4096] per-expert token lists, packed (t<<2)|k
                          // end: 7344640 floats = 29.4 MB

// out layout (floats)
#define OUT_TE   2097152
#define OUT_EPE  2097153
#define OUT_RE   2097281
#define OUT_SR   2097409
#define OUT_VPEN 2097537
#define OUT_UPEN 2097538
#define OUT_AUX  2097539

#define GLDS16(g, l) __builtin_amdgcn_global_load_lds(                        \
    (const __attribute__((address_space(1))) unsigned int*)(g),               \
    (__attribute__((address_space(3))) unsigned int*)(l), 16, 0, 0)

__device__ __forceinline__ ushort f2bf(float f) {   // RNE
    union { float f; uint u; } a; a.f = f;
    uint u = a.u;
    u += 0x7fffu + ((u >> 16) & 1u);
    return (ushort)(u >> 16);
}
__device__ __forceinline__ float bf2f(ushort h) {
    union { uint u; float f; } a; a.u = ((uint)h) << 16;
    return a.f;
}

// ---------------- fused prep: converts + scales + ws-zero (1570 blocks) ----
// blocks [0,1024): convert_x ; [1024,1280): convert_VT ; [1280,1408): convert_UT ;
// [1408,1570): scales (incl. ws-head zero at 1568/1569)
__launch_bounds__(256)
__global__ void prep_kernel(const float* __restrict__ x, const float* __restrict__ V,
                            const float* __restrict__ U, const float* __restrict__ us_in,
                            ushort* __restrict__ xh, ushort* __restrict__ xl,
                            ushort* __restrict__ vht, ushort* __restrict__ vlt,
                            ushort* __restrict__ uht, ushort* __restrict__ ult,
                            float* __restrict__ ws) {
    __shared__ float ts[64][65];
    const int bid = blockIdx.x;
    const int tid = threadIdx.x;

    if (bid < 1024) {                       // convert_x
        const int idx = (bid * 256 + tid) * 8;
        float4 v0 = *(const float4*)(x + idx);
        float4 v1 = *(const float4*)(x + idx + 4);
        float vv[8] = {v0.x, v0.y, v0.z, v0.w, v1.x, v1.y, v1.z, v1.w};
        union { ushort u[8]; uint4 q; } H, L;
#pragma unroll
        for (int j = 0; j < 8; ++j) {
            ushort h = f2bf(vv[j]);
            H.u[j] = h;
            L.u[j] = f2bf(vv[j] - bf2f(h));
        }
        *(uint4*)(xh + idx) = H.q;
        *(uint4*)(xl + idx) = L.q;
    } else if (bid < 1280) {                // convert_VT (64x64 tile transpose)
        const int vb = bid - 1024;
        const int col0 = (vb & 31) * 64;
        const int d0 = (vb >> 5) * 64;
#pragma unroll
        for (int i = 0; i < 16; ++i) {
            int idx = i * 256 + tid;
            int r = idx >> 6, c = idx & 63;
            ts[r][c] = V[(size_t)(d0 + r) * NC + col0 + c];
        }
        __syncthreads();
#pragma unroll
        for (int i = 0; i < 16; ++i) {
            int idx = i * 256 + tid;
            int c2 = idx >> 6, d2 = idx & 63;
            float v = ts[d2][c2];
            ushort h = f2bf(v);
            vht[(size_t)(col0 + c2) * D + d0 + d2] = h;
            vlt[(size_t)(col0 + c2) * D + d0 + d2] = f2bf(v - bf2f(h));
        }
    } else if (bid < 1408) {                // convert_UT (one expert per block)
        const int m = bid - 1280;
        float (*t2)[129] = (float (*)[129])ts;   // 16 x 129 view
        for (int d0 = 0; d0 < D; d0 += 128) {
            __syncthreads();
#pragma unroll
            for (int i = 0; i < 8; ++i) {
                int idx = i * 256 + tid;
                int d2 = idx >> 4, b2 = idx & 15;
                t2[b2][d2] = U[(size_t)m * (D * B) + (size_t)(d0 + d2) * B + b2];
            }
            __syncthreads();
#pragma unroll
            for (int i = 0; i < 8; ++i) {
                int idx = i * 256 + tid;
                int b3 = idx >> 7, d3 = idx & 127;
                float v = t2[b3][d3];
                ushort h = f2bf(v);
                uht[(size_t)((m << 4) + b3) * D + d0 + d3] = h;
                ult[(size_t)((m << 4) + b3) * D + d0 + d3] = f2bf(v - bf2f(h));
            }
        }
    } else {                                // scales + ws-head zero
        const int bx = bid - 1408;
        if (bx >= 160) {
            ws[(bx - 160) * 256 + tid] = 0.0f;
            return;
        }
        if (bx < 32) {
            const int c = bx * 64 + (tid & 63);
            const int dg = tid >> 6;
            float s = 0.0f;
            for (int d = dg; d < D; d += 4) {
                float v = V[(size_t)d * NC + c];
                s = fmaf(v, v, s);
            }
            float (*sh)[64] = (float (*)[64])ts;
            sh[dg][tid & 63] = s;
            __syncthreads();
            if (tid < 64) {
                float t = (sh[0][tid] + sh[1][tid]) + (sh[2][tid] + sh[3][tid]);
                ws[WS_VSCALE + bx * 64 + tid] = 1.0f / sqrtf(t);
            }
        } else {
            const int m = bx - 32;
            const float* p = U + (size_t)m * (D * B);
            float s = 0.0f;
            for (int i = tid; i < D * B; i += 256) {
                float v = p[i];
                s = fmaf(v, v, s);
            }
            float* sh2 = &ts[0][0];
            sh2[tid] = s;
            __syncthreads();
            if (tid < 16) {
                float t = 0.0f;
#pragma unroll
                for (int j = 0; j < 16; ++j) t += sh2[tid + (j << 4)];
                ws[WS_USCALE + (m << 4) + tid] = tanhf(us_in[(m << 4) + tid]) / sqrtf(t);
            }
        }
    }
}

// ---------------- fused MFMA: gemm tiles (blocks 0..511) + gram tiles (512..783)
__launch_bounds__(256)
__global__ void mfma_fused(const ushort* __restrict__ xh, const ushort* __restrict__ xl,
                           const ushort* __restrict__ vht, const ushort* __restrict__ vlt,
                           const ushort* __restrict__ uht, const ushort* __restrict__ ult,
                           float* __restrict__ ws, ushort* __restrict__ rbf) {
    __shared__ ushort smem[32768];   // 2 bufs x 4 tiles x (128 rows x 32 bf16)
    const int bid = blockIdx.x;
    const int tid = threadIdx.x, lane = tid & 63, w = tid >> 6;
    const int wr = w >> 1, wc = w & 1;
    const int r15 = lane & 15, q = lane >> 4;
    const int srl = lane >> 2;
    const int skq = (lane & 3) ^ ((lane >> 3) & 3);
    const int perm8 = (q ^ ((r15 >> 1) & 3)) * 8;

    const int is_gemm = bid < 512;
    const ushort* srcs[4];
    int rbase[4];
    int gi = 0, gj = 0, which = 0;
    if (is_gemm) {
        const int tokB = (bid & 31) * 128, colB = (bid >> 5) * 128;
        srcs[0] = xh; srcs[1] = xl; srcs[2] = vht; srcs[3] = vlt;
        rbase[0] = tokB; rbase[1] = tokB; rbase[2] = colB; rbase[3] = colB;
    } else {
        int t = bid - 512;
        which = t >= 136;
        if (which) t -= 136;
        int bi = 0, rem = 16;
        while (t >= rem) { t -= rem; --rem; ++bi; }
        gi = bi; gj = bi + t;
        const ushort* ht = which ? uht : vht;
        const ushort* lt = which ? ult : vlt;
        srcs[0] = ht; srcs[1] = lt; srcs[2] = ht; srcs[3] = lt;
        rbase[0] = gi * 128; rbase[1] = gi * 128; rbase[2] = gj * 128; rbase[3] = gj * 128;
    }

    floatx4 acc[4][4];
#pragma unroll
    for (int i = 0; i < 4; ++i)
#pragma unroll
        for (int j = 0; j < 4; ++j) acc[i][j] = (floatx4){0.f, 0.f, 0.f, 0.f};

    auto stage = [&](int buf, int c) {
        const int kb = c * 32 + skq * 8;
#pragma unroll
        for (int tI = 0; tI < 4; ++tI) {
            const ushort* s = srcs[tI] + (size_t)rbase[tI] * D + kb;
#pragma unroll
            for (int sub = 0; sub < 2; ++sub) {
                const int row16 = w * 32 + sub * 16;
                GLDS16(s + (size_t)(row16 + srl) * D,
                       &smem[buf * 16384 + tI * 4096 + row16 * 32]);
            }
        }
    };

    stage(0, 0);
    for (int c = 0; c < 16; ++c) {
        __syncthreads();
        if (c < 15) stage((c + 1) & 1, c + 1);
        const ushort* bp = &smem[(c & 1) * 16384];
        short8 ah[4], al[4], bh[4], bl[4];
#pragma unroll
        for (int s = 0; s < 4; ++s) {
            const int ra = (wr * 64 + s * 16 + r15) * 32 + perm8;
            ah[s] = *(const short8*)&bp[ra];
            al[s] = *(const short8*)&bp[4096 + ra];
            const int rb = (wc * 64 + s * 16 + r15) * 32 + perm8;
            bh[s] = *(const short8*)&bp[8192 + rb];
            bl[s] = *(const short8*)&bp[12288 + rb];
        }
#pragma unroll
        for (int st = 0; st < 4; ++st)
#pragma unroll
            for (int sc = 0; sc < 4; ++sc) {
                acc[st][sc] = __builtin_amdgcn_mfma_f32_16x16x32_bf16(ah[st], bh[sc], acc[st][sc], 0, 0, 0);
                acc[st][sc] = __builtin_amdgcn_mfma_f32_16x16x32_bf16(ah[st], bl[sc], acc[st][sc], 0, 0, 0);
                acc[st][sc] = __builtin_amdgcn_mfma_f32_16x16x32_bf16(al[st], bh[sc], acc[st][sc], 0, 0, 0);
            }
    }

    if (is_gemm) {
        const int tok0 = (bid & 31) * 128 + wr * 64, col0 = (bid >> 5) * 128 + wc * 64;
#pragma unroll
        for (int sc = 0; sc < 4; ++sc) {
            const int colg = col0 + sc * 16 + r15;
            const float vs = ws[WS_VSCALE + colg];
            const int ex = colg >> 4;
#pragma unroll
            for (int st = 0; st < 4; ++st) {
                const int rowb = tok0 + st * 16 + q * 4;
                float r0 = acc[st][sc][0] * vs;
                float r1 = acc[st][sc][1] * vs;
                float r2 = acc[st][sc][2] * vs;
                float r3 = acc[st][sc][3] * vs;
                rbf[(size_t)(rowb + 0) * NC + colg] = f2bf(r0);
                rbf[(size_t)(rowb + 1) * NC + colg] = f2bf(r1);
                rbf[(size_t)(rowb + 2) * NC + colg] = f2bf(r2);
                rbf[(size_t)(rowb + 3) * NC + colg] = f2bf(r3);
                float e0 = r0 * r0, e1 = r1 * r1, e2 = r2 * r2, e3 = r3 * r3;
#pragma unroll
                for (int mk = 1; mk < 16; mk <<= 1) {
                    e0 += __shfl_xor(e0, mk);
                    e1 += __shfl_xor(e1, mk);
                    e2 += __shfl_xor(e2, mk);
                    e3 += __shfl_xor(e3, mk);
                }
                if (r15 == 0) {
                    float* ep = ws + WS_E_F + (size_t)rowb * M + ex;
                    ep[0] = e0; ep[M] = e1; ep[2 * M] = e2; ep[3 * M] = e3;
                }
            }
        }
    } else {
        const float* scl = ws + (which ? WS_USCALE : WS_VSCALE);
        float* sum_out = ws + (which ? WS_USUM : WS_VSUM);
        float local = 0.0f;
#pragma unroll
        for (int sc = 0; sc < 4; ++sc) {
            const int colg = gj * 128 + wc * 64 + sc * 16 + r15;
            const float scj = scl[colg];
#pragma unroll
            for (int st = 0; st < 4; ++st) {
#pragma unroll
                for (int reg = 0; reg < 4; ++reg) {
                    const int rowg = gi * 128 + wr * 64 + st * 16 + q * 4 + reg;
                    float g = acc[st][sc][reg] * scl[rowg] * scj;
                    if (rowg == colg) g -= 1.0f;
                    local += fabsf(g);
                }
            }
        }
        if (gi < gj) local *= 2.0f;
#pragma unroll
        for (int mk = 1; mk < 64; mk <<= 1) local += __shfl_xor(local, mk);
        __shared__ float red[4];
        if (lane == 0) red[w] = local;
        __syncthreads();
        if (tid == 0) atomicAdd(sum_out, (red[0] + red[1]) + (red[2] + red[3]));
    }
}

// Wave-per-token top-4: packed u64 keys (val_bits<<32 | ~idx — exact jax tie
// order), sorted-quadruple butterfly: 6 steps, each = bitonic halver + 4-sort.
__launch_bounds__(256)
__global__ void topk_kernel(float* __restrict__ ws) {
    const int tid = threadIdx.x, lane = tid & 63, w = tid >> 6;
    const int t = blockIdx.x * 4 + w;
    int* icnt = (int*)ws + WS_CNT_I;
    int* ilist = (int*)(ws + WS_LIST_F);

    const float2 ev = *(const float2*)(ws + WS_E_F + (size_t)t * M + lane * 2);
    const uint i0 = (uint)(lane * 2), i1 = i0 + 1;
    u64 k0 = ((u64)__float_as_uint(ev.x) << 32) | (uint)(~i0);
    u64 k1 = ((u64)__float_as_uint(ev.y) << 32) | (uint)(~i1);
    u64 s0 = k0 > k1 ? k0 : k1;
    u64 s1 = k0 > k1 ? k1 : k0;
    u64 s2 = 0, s3 = 0;

#pragma unroll
    for (int mk = 1; mk < 64; mk <<= 1) {
        u64 o0 = __shfl_xor(s0, mk);
        u64 o1 = __shfl_xor(s1, mk);
        u64 o2 = __shfl_xor(s2, mk);
        u64 o3 = __shfl_xor(s3, mk);
        u64 c0 = s0 > o3 ? s0 : o3;
        u64 c1 = s1 > o2 ? s1 : o2;
        u64 c2 = s2 > o1 ? s2 : o1;
        u64 c3 = s3 > o0 ? s3 : o0;
        u64 d0 = c0 > c2 ? c0 : c2, d2 = c0 > c2 ? c2 : c0;
        u64 d1 = c1 > c3 ? c1 : c3, d3 = c1 > c3 ? c3 : c1;
        s0 = d0 > d1 ? d0 : d1; s1 = d0 > d1 ? d1 : d0;
        s2 = d2 > d3 ? d2 : d3; s3 = d2 > d3 ? d3 : d2;
    }

    if (lane < 4) {
        u64 key = (lane == 0) ? s0 : (lane == 1) ? s1 : (lane == 2) ? s2 : s3;
        const int e = (int)(~(uint)key);
        const float val = __uint_as_float((uint)(key >> 32));
        atomicAdd(&ws[WS_EACC + e], val);
        atomicAdd(&ws[WS_CACC + e], 1.0f);
        int pos = atomicAdd(&icnt[e], 1);
        ilist[(e << 12) + pos] = (t << 2) | lane;
    }
}

// Expert-major contributions: contrib[t][k][d] (bf16 pairs packed in uint).
__launch_bounds__(256)
__global__ void expert_contrib_kernel(const float* __restrict__ U,
                                      const ushort* __restrict__ rbf,
                                      const float* __restrict__ ws,
                                      uint* __restrict__ contrib) {
    const int e = blockIdx.x;
    const int tid = threadIdx.x;
    const int cnt = ((const int*)ws)[WS_CNT_I + e];
    if ((int)blockIdx.y >= cnt) return;

    float usc[16];
#pragma unroll
    for (int b = 0; b < 16; ++b) usc[b] = ws[WS_USCALE + (e << 4) + b];

    const float* Up = U + (size_t)e * (D * B);
    float u0[16], u1[16];
#pragma unroll
    for (int qd = 0; qd < 4; ++qd) {
        float4 a = *(const float4*)(Up + (size_t)(2 * tid) * B + qd * 4);
        float4 b4 = *(const float4*)(Up + (size_t)(2 * tid + 1) * B + qd * 4);
        u0[qd * 4 + 0] = a.x * usc[qd * 4 + 0];
        u0[qd * 4 + 1] = a.y * usc[qd * 4 + 1];
        u0[qd * 4 + 2] = a.z * usc[qd * 4 + 2];
        u0[qd * 4 + 3] = a.w * usc[qd * 4 + 3];
        u1[qd * 4 + 0] = b4.x * usc[qd * 4 + 0];
        u1[qd * 4 + 1] = b4.y * usc[qd * 4 + 1];
        u1[qd * 4 + 2] = b4.z * usc[qd * 4 + 2];
        u1[qd * 4 + 3] = b4.w * usc[qd * 4 + 3];
    }

    const int* ilist = (const int*)(ws + WS_LIST_F) + (e << 12);
    int i = blockIdx.y;
    int pk = (i < cnt) ? ilist[i] : 0;
    while (i < cnt) {
        const int t = pk >> 2, k = pk & 3;
        const ushort* rp = rbf + (size_t)t * NC + (e << 4);
        union { ushort u[16]; uint4 q[2]; } R;
        R.q[0] = *(const uint4*)(rp);
        R.q[1] = *(const uint4*)(rp + 8);
        const int inext = i + 4;
        if (inext < cnt) pk = ilist[inext];
        float acc0 = 0.0f, acc1 = 0.0f;
#pragma unroll
        for (int b = 0; b < 16; ++b) {
            const float wv = bf2f(R.u[b]);
            acc0 = fmaf(u0[b], wv, acc0);
            acc1 = fmaf(u1[b], wv, acc1);
        }
        contrib[(size_t)((t << 2) + k) * 256 + tid] =
            (uint)f2bf(acc0) | ((uint)f2bf(acc1) << 16);
        i = inext;
    }
}

// blocks 0..1023: out = x + sum_k contrib  ; block 1024: finalize scalars
__launch_bounds__(256)
__global__ void combine_kernel(const float* __restrict__ x,
                               const uint* __restrict__ contrib,
                               const float* __restrict__ ws,
                               float* __restrict__ out) {
    if (blockIdx.x == 1024) {               // finalize
        const int m = threadIdx.x;
        if (m >= 128) return;
        float e = ws[WS_EACC + m] * (1.0f / (float)NTOK);
        float c = ws[WS_CACC + m] * (1.0f / (float)NTOK);
        float s = e;
#pragma unroll
        for (int off = 32; off > 0; off >>= 1) s += __shfl_down(s, off);
        __shared__ float sh[2];
        if ((m & 63) == 0) sh[m >> 6] = s;
        __syncthreads();
        float total = sh[0] + sh[1];
        float total_energy = fmaxf(total, 1e-12f);
        out[OUT_EPE + m] = e;
        out[OUT_RE + m] = e / total_energy;
        out[OUT_SR + m] = c;
        if (m == 0) {
            out[OUT_TE] = total_energy;
            float inv_n2 = 1.0f / ((float)NC * (float)NC);
            float sqrtD = sqrtf((float)D);
            float vpen = ws[WS_VSUM] * inv_n2 * sqrtD;
            float upen = ws[WS_USUM] * inv_n2 * sqrtD;
            out[OUT_VPEN] = vpen;
            out[OUT_UPEN] = upen;
            out[OUT_AUX] = 0.01f * vpen - total_energy;
        }
        return;
    }

    const int gid = blockIdx.x * 256 + threadIdx.x;
    const int t = gid >> 6;
    const int dq = (gid & 63) << 3;
    const uint4* cp = (const uint4*)contrib;

    float s[8];
    float4 x0 = *(const float4*)(x + (size_t)t * D + dq);
    float4 x1 = *(const float4*)(x + (size_t)t * D + dq + 4);
    s[0] = x0.x; s[1] = x0.y; s[2] = x0.z; s[3] = x0.w;
    s[4] = x1.x; s[5] = x1.y; s[6] = x1.z; s[7] = x1.w;
#pragma unroll
    for (int k = 0; k < KSEL; ++k) {
        uint4 cvec = cp[(size_t)((t << 2) + k) * 64 + (dq >> 3)];
        uint cc[4] = {cvec.x, cvec.y, cvec.z, cvec.w};
#pragma unroll
        for (int j = 0; j < 4; ++j) {
            s[2 * j]     += bf2f((ushort)(cc[j] & 0xffffu));
            s[2 * j + 1] += bf2f((ushort)(cc[j] >> 16));
        }
    }
    float* op = out + (size_t)t * D + dq;
    *(float4*)(op)     = make_float4(s[0], s[1], s[2], s[3]);
    *(float4*)(op + 4) = make_float4(s[4], s[5], s[6], s[7]);
}

extern "C" void kernel_launch(void* const* d_in, const int* in_sizes, int n_in,
                              void* d_out, int out_size, void* d_ws, size_t ws_size,
                              hipStream_t stream) {
    const float* x  = (const float*)d_in[0];
    const float* V  = (const float*)d_in[1];
    const float* U  = (const float*)d_in[2];
    const float* us = (const float*)d_in[3];
    float* out = (float*)d_out;
    float* ws  = (float*)d_ws;

    ushort* xh  = (ushort*)(ws + WS_XH_F);
    ushort* xl  = (ushort*)(ws + WS_XL_F);
    ushort* vht = (ushort*)(ws + WS_VHT_F);
    ushort* vlt = (ushort*)(ws + WS_VLT_F);
    ushort* uht = (ushort*)(ws + WS_UHT_F);
    ushort* ult = (ushort*)(ws + WS_ULT_F);
    ushort* rbf = (ushort*)(ws + WS_RBF_F);
    uint* contrib = (uint*)(ws + WS_XH_F);   // reuses xh..ult after mfma_fused

    prep_kernel<<<1570, 256, 0, stream>>>(x, V, U, us, xh, xl, vht, vlt, uht, ult, ws);
    mfma_fused<<<784, 256, 0, stream>>>(xh, xl, vht, vlt, uht, ult, ws, rbf);
    topk_kernel<<<NTOK / 4, 256, 0, stream>>>(ws);
    expert_contrib_kernel<<<dim3(128, 4), 256, 0, stream>>>(U, rbf, ws, contrib);
    combine_kernel<<<1025, 256, 0, stream>>>(x, contrib, ws, out);
}